// Round 8
// baseline (871.681 us; speedup 1.0000x reference)
//
#include <hip/hip_runtime.h>
#include <hip/hip_bf16.h>
#include <math.h>

// ---------------- problem constants ----------------
#define NN 30000
#define EE 480000
#define ET (EE + NN)   // edges + self loops = 510000
#define NEG_SLOPE 0.2f
#define BN_EPS 1e-5f

struct LayerCfg { int cin, C, H; };
static const LayerCfg g_cfg[5] = {
    {128, 100, 5}, {500, 50, 5}, {250, 32, 4}, {128, 8, 4}, {32, 1, 1}
};

typedef short short8 __attribute__((ext_vector_type(8)));
typedef float f32x4 __attribute__((ext_vector_type(4)));

__device__ __forceinline__ unsigned short f2bf(float f) {
    unsigned int u = __builtin_bit_cast(unsigned int, f);
    u = (u + 0x7FFFu + ((u >> 16) & 1u)) >> 16;
    return (unsigned short)u;
}
__device__ __forceinline__ float bf2f(unsigned short h) {
    unsigned int u = ((unsigned int)h) << 16;
    return __builtin_bit_cast(float, u);
}
__device__ __forceinline__ float bf_lo(unsigned int d) {
    return __builtin_bit_cast(float, d << 16);
}
__device__ __forceinline__ float bf_hi(unsigned int d) {
    return __builtin_bit_cast(float, d & 0xffff0000u);
}

// ---------------- all-layer weight prep args ----------------

struct PrepArgs {
    const float* W[5];
    const float* We[5];
    const float* ae[5];
    unsigned short* bh[5];
    unsigned short* bl[5];
    float* wedot;            // out: [5][8]
    int K[5], N[5], Kp[5], Np[5], C[5], H[5];
};

// fused independent prep: build_edges histogram + edge-weight sum + weight transpose.
static const int EBLK = (ET + 255) / 256;

__global__ void prep_fused_kernel(const int* __restrict__ ei, int* __restrict__ rank,
                                  int* __restrict__ cnt, const float* __restrict__ ew,
                                  float* __restrict__ esum, PrepArgs a) {
    __shared__ float sdata[256];
    __shared__ float tile[32][33];
    int b = blockIdx.x;
    int tid = threadIdx.x;

    if (b < EBLK) {
        int e = b * 256 + tid;
        if (e < ET) {
            int d = (e < EE) ? ei[EE + e] : (e - EE);
            rank[e] = atomicAdd(&cnt[d], 1);
        }
        return;
    }
    b -= EBLK;
    if (b < 256) {
        float s = 0.f;
        for (int i = b * 256 + tid; i < EE; i += 65536)
            s += ew[i];
        sdata[tid] = s;
        __syncthreads();
        for (int off = 128; off > 0; off >>= 1) {
            if (tid < off) sdata[tid] += sdata[tid + off];
            __syncthreads();
        }
        if (tid == 0) atomicAdd(esum, sdata[0]);
        return;
    }
    b -= 256;
    int bx = b & 15, by = (b >> 4) & 15, bz = b >> 8;
    int l = bz;
    int tx = tid & 31, ty = tid >> 5;      // 32 x 8
    if (bx == 0 && by == 0 && ty == 0 && tx < 8) {
        int hd = tx;
        if (hd < a.H[l]) {
            int C = a.C[l];
            const float* We = a.We[l] + hd * C;
            const float* ae = a.ae[l] + hd * C;
            float s = 0.f;
            for (int c = 0; c < C; c++) s += We[c] * ae[c];
            a.wedot[l * 8 + hd] = s;
        }
    }
    int Kp = a.Kp[l], Np = a.Np[l], K = a.K[l], N = a.N[l];
    int kb = bx * 32, nb = by * 32;
    if (kb >= Kp || nb >= Np) return;
    const float* B = a.W[l];
    unsigned short* Bth = a.bh[l];
    unsigned short* Btl = a.bl[l];
#pragma unroll
    for (int i = 0; i < 4; i++) {
        int k = kb + ty + i * 8, n = nb + tx;
        tile[ty + i * 8][tx] = (k < K && n < N) ? B[(size_t)k * N + n] : 0.f;
    }
    __syncthreads();
#pragma unroll
    for (int i = 0; i < 4; i++) {
        int n = nb + ty + i * 8, k = kb + tx;
        if (n < Np && k < Kp) {
            float v = tile[tx][ty + i * 8];
            unsigned short hi = f2bf(v);
            unsigned short lo = f2bf(v - bf2f(hi));
            size_t idx = (size_t)n * Kp + k;
            Bth[idx] = hi;
            Btl[idx] = lo;
        }
    }
}

// exclusive prefix over cnt -> off
__global__ void scan_kernel(const int* __restrict__ cnt, int* __restrict__ off) {
    __shared__ int lsum[1024];
    const int T = 1024;
    int t = threadIdx.x;
    int chunk = (NN + T - 1) / T;
    int base = t * chunk;
    int end = min(NN, base + chunk);
    int s = 0;
    for (int i = base; i < end; i++) s += cnt[i];
    lsum[t] = s;
    __syncthreads();
    for (int d = 1; d < T; d <<= 1) {
        int v = (t >= d) ? lsum[t - d] : 0;
        __syncthreads();
        lsum[t] += v;
        __syncthreads();
    }
    int run = (t == 0) ? 0 : lsum[t - 1];
    for (int i = base; i < end; i++) {
        off[i] = run;
        run += cnt[i];
    }
    if (t == 0) off[NN] = ET;
}

// scatter edges to CSR order via precomputed rank — NO atomics
__global__ void fill_kernel(const int* __restrict__ ei, const int* __restrict__ rank,
                            const float* __restrict__ ew, const float* __restrict__ esum,
                            const int* __restrict__ off,
                            int* __restrict__ csr_src, float* __restrict__ csr_ea) {
    int e = blockIdx.x * blockDim.x + threadIdx.x;
    if (e >= ET) return;
    int sv, d;
    if (e < EE) { sv = ei[e]; d = ei[EE + e]; }
    else        { sv = e - EE; d = e - EE; }
    int p = off[d] + rank[e];
    csr_src[p] = sv;
    csr_ea[p]  = (e < EE) ? ew[e] : esum[0] * (1.0f / (float)EE);
}

// ---------------- split-bf16 MFMA GEMM with optional fused BN+ReLU on A ----------------
#define GBM 128
#define GBNT 128
#define GBK 32
#define ASTR 36
__global__ __launch_bounds__(256) void gemm_split_kernel(const float* __restrict__ A,
                                                         const unsigned short* __restrict__ Bt_hi,
                                                         const unsigned short* __restrict__ Bt_lo,
                                                         float* __restrict__ Cm,
                                                         unsigned short* __restrict__ Ch16,
                                                         int M, int Kp, int Nc,
                                                         const float* __restrict__ colsum,
                                                         const float* __restrict__ colsumsq,
                                                         const float* __restrict__ g,
                                                         const float* __restrict__ beta,
                                                         int D) {
    __shared__ short AsH[GBM * ASTR];
    __shared__ short AsL[GBM * ASTR];
    __shared__ short BsH[GBNT * ASTR];
    __shared__ short BsL[GBNT * ASTR];
    __shared__ float sscale[512];
    __shared__ float sshift[512];
    int tid = threadIdx.x;
    bool bn = (colsum != nullptr);
    if (bn) {
        for (int c = tid; c < Kp; c += 256) {
            float sc = 0.f, sh = 0.f;
            if (c < D) {
                float mu = colsum[c] * (1.0f / (float)NN);
                float var = colsumsq[c] * (1.0f / (float)NN) - mu * mu;
                sc = g[c] * rsqrtf(var + BN_EPS);
                sh = beta[c] - mu * sc;
            }
            sscale[c] = sc;
            sshift[c] = sh;
        }
        __syncthreads();
    }
    int wave = tid >> 6, lane = tid & 63;
    int q = lane >> 4, r = lane & 15;
    int m0 = blockIdx.y * GBM, n0 = blockIdx.x * GBNT;
    int wm = (wave & 1) * 64, wn = (wave >> 1) * 64;
    f32x4 acc[4][4];
#pragma unroll
    for (int i = 0; i < 4; i++)
#pragma unroll
        for (int j = 0; j < 4; j++) acc[i][j] = (f32x4)(0.f);

    int arow2 = tid >> 1;
    int acol2 = (tid & 1) * 16;
    int brow = tid >> 2;
    int bcol = (tid & 3) * 8;

    int ksteps = Kp / GBK;
    for (int ks = 0; ks < ksteps; ks++) {
        int k0 = ks * GBK;
        {
            int m = m0 + arow2;
            float v[16];
            if (m < M) {
                const float* Ap = A + (size_t)m * Kp + k0 + acol2;
                float4 f0 = *(const float4*)(Ap);
                float4 f1 = *(const float4*)(Ap + 4);
                float4 f2 = *(const float4*)(Ap + 8);
                float4 f3 = *(const float4*)(Ap + 12);
                v[0]=f0.x; v[1]=f0.y; v[2]=f0.z; v[3]=f0.w;
                v[4]=f1.x; v[5]=f1.y; v[6]=f1.z; v[7]=f1.w;
                v[8]=f2.x; v[9]=f2.y; v[10]=f2.z; v[11]=f2.w;
                v[12]=f3.x; v[13]=f3.y; v[14]=f3.z; v[15]=f3.w;
                if (bn) {
                    int cb = k0 + acol2;
#pragma unroll
                    for (int i = 0; i < 16; i++)
                        v[i] = fmaxf(v[i] * sscale[cb + i] + sshift[cb + i], 0.f);
                }
            } else {
#pragma unroll
                for (int i = 0; i < 16; i++) v[i] = 0.f;
            }
#pragma unroll
            for (int i = 0; i < 16; i++) {
                unsigned short hi = f2bf(v[i]);
                unsigned short lo = f2bf(v[i] - bf2f(hi));
                AsH[arow2 * ASTR + acol2 + i] = (short)hi;
                AsL[arow2 * ASTR + acol2 + i] = (short)lo;
            }
        }
#pragma unroll
        for (int p = 0; p < 2; p++) {
            int row = p * 64 + brow;
            size_t gidx = (size_t)(n0 + row) * Kp + k0 + bcol;
            *((uint4*)(BsH + row * ASTR + bcol)) = *((const uint4*)(Bt_hi + gidx));
            *((uint4*)(BsL + row * ASTR + bcol)) = *((const uint4*)(Bt_lo + gidx));
        }
        __syncthreads();
        short8 ah[4], al[4], bh[4], bl[4];
#pragma unroll
        for (int i = 0; i < 4; i++) {
            ah[i] = *((const short8*)(AsH + (wm + i * 16 + r) * ASTR + q * 8));
            al[i] = *((const short8*)(AsL + (wm + i * 16 + r) * ASTR + q * 8));
        }
#pragma unroll
        for (int j = 0; j < 4; j++) {
            bh[j] = *((const short8*)(BsH + (wn + j * 16 + r) * ASTR + q * 8));
            bl[j] = *((const short8*)(BsL + (wn + j * 16 + r) * ASTR + q * 8));
        }
#pragma unroll
        for (int i = 0; i < 4; i++)
#pragma unroll
            for (int j = 0; j < 4; j++) {
                acc[i][j] = __builtin_amdgcn_mfma_f32_16x16x32_bf16(ah[i], bh[j], acc[i][j], 0, 0, 0);
                acc[i][j] = __builtin_amdgcn_mfma_f32_16x16x32_bf16(ah[i], bl[j], acc[i][j], 0, 0, 0);
                acc[i][j] = __builtin_amdgcn_mfma_f32_16x16x32_bf16(al[i], bh[j], acc[i][j], 0, 0, 0);
            }
        __syncthreads();
    }
#pragma unroll
    for (int i = 0; i < 4; i++) {
#pragma unroll
        for (int j = 0; j < 4; j++) {
#pragma unroll
            for (int reg = 0; reg < 4; reg++) {
                int mrow = m0 + wm + i * 16 + q * 4 + reg;
                int ncol = n0 + wn + j * 16 + r;
                if (mrow < M && ncol < Nc) {
                    float val = acc[i][j][reg];
                    if (Cm)   Cm[(size_t)mrow * Nc + ncol] = val;
                    if (Ch16) Ch16[(size_t)mrow * Nc + ncol] = f2bf(val);
                }
            }
        }
    }
}

// layer-5 fused GEMV
__global__ void gemv_l5_kernel(const float* __restrict__ X, const float* __restrict__ W,
                               const float* __restrict__ a_s, const float* __restrict__ a_d,
                               float* __restrict__ h, float* __restrict__ al_src,
                               float* __restrict__ al_dst) {
    __shared__ float w[32];
    if (threadIdx.x < 32) w[threadIdx.x] = W[threadIdx.x];
    __syncthreads();
    int n = blockIdx.x * blockDim.x + threadIdx.x;
    if (n >= NN) return;
    const float* row = X + (size_t)n * 32;
    float s = 0.f;
#pragma unroll
    for (int i = 0; i < 8; i++) {
        float4 f = *(const float4*)(row + i * 4);
        s += f.x * w[i * 4] + f.y * w[i * 4 + 1] + f.z * w[i * 4 + 2] + f.w * w[i * 4 + 3];
    }
    h[n] = s;
    al_src[n] = s * a_s[0];
    al_dst[n] = s * a_d[0];
}

// wave-per-node attention dots, bf16 h (layers 1-4); HCp = padded row pitch
__global__ void al_wave_h16_kernel(const unsigned short* __restrict__ h16,
                                   const float* __restrict__ a_s,
                                   const float* __restrict__ a_d,
                                   float* __restrict__ al_src, float* __restrict__ al_dst,
                                   int H, int C, int HCp) {
    int w = (blockIdx.x * blockDim.x + threadIdx.x) >> 6;
    int lane = threadIdx.x & 63;
    if (w >= NN) return;
    const unsigned short* row = h16 + (size_t)w * HCp;
    float s1[5] = {0.f, 0.f, 0.f, 0.f, 0.f};
    float s2[5] = {0.f, 0.f, 0.f, 0.f, 0.f};
#pragma unroll
    for (int hd = 0; hd < 5; hd++) {
        if (hd >= H) break;
        int base = hd * C;
        for (int c = lane * 2; c < C; c += 128) {
            unsigned int u = *(const unsigned int*)(row + base + c);
            float v0 = bf2f((unsigned short)(u & 0xffffu));
            float v1 = bf2f((unsigned short)(u >> 16));
            s1[hd] += v0 * a_s[base + c] + v1 * a_s[base + c + 1];
            s2[hd] += v0 * a_d[base + c] + v1 * a_d[base + c + 1];
        }
    }
#pragma unroll
    for (int hd = 0; hd < 5; hd++) {
        if (hd >= H) break;
#pragma unroll
        for (int off = 32; off > 0; off >>= 1) {
            s1[hd] += __shfl_xor(s1[hd], off, 64);
            s2[hd] += __shfl_xor(s2[hd], off, 64);
        }
    }
    if (lane == 0) {
#pragma unroll
        for (int hd = 0; hd < 5; hd++) {
            if (hd >= H) break;
            al_src[(size_t)w * H + hd] = s1[hd];
            al_dst[(size_t)w * H + hd] = s2[hd];
        }
    }
}

// SINGLE-PASS attn: writes UNNORMALIZED exp(logit) to alpha_t and 1/den to
// inv_den[n*H+hd]; the aggregate multiplies by inv_den in its epilogue.
__global__ void attn_kernel(const float* __restrict__ al_src,
                            const float* __restrict__ al_dst,
                            const int* __restrict__ csr_src,
                            const float* __restrict__ csr_ea,
                            const float* __restrict__ we_dot,
                            const int* __restrict__ off,
                            float* __restrict__ alpha_t,
                            float* __restrict__ inv_den, int H, int NH) {
    int t = blockIdx.x * blockDim.x + threadIdx.x;
    if (t >= NH) return;
    int n = t / H, hd = t - n * H;
    int s = off[n], e = off[n + 1];
    float ad = al_dst[(size_t)n * H + hd];
    float wd = we_dot[hd];
    float* arow = alpha_t + (size_t)hd * ET;
    float den = 0.f;
    int p = s;
    for (; p + 3 < e; p += 4) {
        int s0 = csr_src[p], s1 = csr_src[p + 1], s2 = csr_src[p + 2], s3 = csr_src[p + 3];
        float w0 = csr_ea[p], w1 = csr_ea[p + 1], w2 = csr_ea[p + 2], w3 = csr_ea[p + 3];
        float l0 = al_src[(size_t)s0 * H + hd] + ad + w0 * wd;
        float l1 = al_src[(size_t)s1 * H + hd] + ad + w1 * wd;
        float l2 = al_src[(size_t)s2 * H + hd] + ad + w2 * wd;
        float l3 = al_src[(size_t)s3 * H + hd] + ad + w3 * wd;
        l0 = (l0 >= 0.f) ? l0 : NEG_SLOPE * l0;
        l1 = (l1 >= 0.f) ? l1 : NEG_SLOPE * l1;
        l2 = (l2 >= 0.f) ? l2 : NEG_SLOPE * l2;
        l3 = (l3 >= 0.f) ? l3 : NEG_SLOPE * l3;
        float e0 = __expf(l0), e1 = __expf(l1), e2 = __expf(l2), e3 = __expf(l3);
        arow[p] = e0; arow[p + 1] = e1; arow[p + 2] = e2; arow[p + 3] = e3;
        den += e0 + e1 + e2 + e3;
    }
    for (; p < e; p++) {
        float lg = al_src[(size_t)csr_src[p] * H + hd] + ad + csr_ea[p] * wd;
        lg = (lg >= 0.f) ? lg : NEG_SLOPE * lg;
        float ex = __expf(lg);
        arow[p] = ex;
        den += ex;
    }
    inv_den[t] = 1.f / fmaxf(den, 1e-16f);
}

// ---------------- slab-partitioned gather aggregate, LDS-staged edges ----------------
// 4 cols/lane. Slab pinned to an XCD via blockIdx&7. Pre-multiplied byte offsets
// + alpha head-rows staged in LDS (cnt-bounded), bank-conflict-free strides.
// NEW r8: fused BN column stats — per-block LDS reduction (bn_s/bn_q) then one
// global atomicAdd per column; removes the separate bn_stats pass (106MB reread).
#define AGG_T 64
#define IDX_STR 68
#define AL_ROW 68
__global__ void aggregate_slab_lds_kernel(const unsigned short* __restrict__ h16,
                                          const float* __restrict__ alpha_t,
                                          const int* __restrict__ off,
                                          const int* __restrict__ csr_src,
                                          const float* __restrict__ bias,
                                          const float* __restrict__ inv_den,
                                          float* __restrict__ out,
                                          int C, int H, int HC, int hp,
                                          int lns, int lcps, int npr, int nhs,
                                          int algstr, int tight,
                                          float* __restrict__ cs_out,
                                          float* __restrict__ cq_out,
                                          int relu, int opitch) {
    extern __shared__ char smem[];
    int cps = 1 << lcps;
    int G = 256 >> lcps;                         // nodes per block
    int* sidx = (int*)smem;                      // [G][IDX_STR]
    float* sal = (float*)(smem + (size_t)G * IDX_STR * 4);  // [G][algstr]
    __shared__ int s_maxt;
    __shared__ float bn_s[64];
    __shared__ float bn_q[64];

    int vs = blockIdx.x & 7;
    int nb = blockIdx.x >> 3;
    int slab = vs & ((1 << lns) - 1);
    int rep  = vs >> lns;
    int tid = threadIdx.x;
    int lc = tid & (cps - 1);
    int g = tid >> lcps;                         // node slot within block
    int nl = nb * G + g;
    bool active = (nl < npr);
    int n = rep * npr + (active ? nl : 0);

    int slab_j = slab << (lcps + 2);
    int j = slab_j + (lc << 2);
    int hlo = slab_j / C;
    int hhi = (slab_j + (cps << 2) - 1) / C;
    if (hhi > H - 1) hhi = H - 1;
    int nval = hhi - hlo + 1;                    // valid alpha rows staged

    int hdA = j / C;
    int hdB = (j + 3) / C;
    int bnd = (hdA + 1) * C - j;
    bnd = (bnd > 4) ? 4 : bnd;
    int selA = hdA - hlo; if (selA >= nhs) selA = nhs - 1;
    int selB = hdB - hlo; if (selB >= nhs) selB = nhs - 1;
    int hA = (hdA < H) ? hdA : H - 1;            // clamped heads for inv_den
    int hB = (hdB < H) ? hdB : H - 1;

    int s = active ? off[n] : 0;
    int e = active ? off[n + 1] : 0;
    int nt = (e - s + AGG_T - 1) / AGG_T;

    if (tid == 0) s_maxt = 0;
    if (tid < 64) { bn_s[tid] = 0.f; bn_q[tid] = 0.f; }
    __syncthreads();
    if (lc == 0 && active && nt > 0) atomicMax(&s_maxt, nt);
    __syncthreads();
    int maxt = s_maxt;

    int hpb = hp << 1;                           // bytes per h16 row
    const char* hb = (const char*)(h16 + j);
    int* myidx = sidx + g * IDX_STR;
    float* myal = sal + (size_t)g * algstr;
    float ac0 = 0.f, ac1 = 0.f, ac2 = 0.f, ac3 = 0.f;

    for (int t = 0; t < maxt; t++) {
        int base = s + t * AGG_T;
        int cnt = e - base;
        if (cnt < 0) cnt = 0;
        if (cnt > AGG_T) cnt = AGG_T;
        __syncthreads();   // protect prior-iteration LDS reads before overwrite
        for (int q = lc; q < cnt; q += cps)
            myidx[q] = csr_src[base + q] * hpb;
        for (int r = 0; r < nhs; r++) {
            bool hv = (r < nval);
            const float* ar = alpha_t + (size_t)(hlo + r) * ET;
            float* dst = myal + r * AL_ROW;
            for (int q = lc; q < cnt; q += cps)
                dst[q] = hv ? ar[base + q] : 0.f;
        }
        __syncthreads();
        if (tight) {
            const float* aA = myal + selA * AL_ROW;
            int q = 0;
            for (; q + 3 < cnt; q += 4) {
                int b0 = myidx[q], b1 = myidx[q + 1], b2 = myidx[q + 2], b3 = myidx[q + 3];
                float a0 = aA[q], a1 = aA[q + 1], a2 = aA[q + 2], a3 = aA[q + 3];
                ushort4 u0 = *(const ushort4*)(hb + b0);
                ushort4 u1 = *(const ushort4*)(hb + b1);
                ushort4 u2 = *(const ushort4*)(hb + b2);
                ushort4 u3 = *(const ushort4*)(hb + b3);
                ac0 += a0 * bf2f(u0.x); ac1 += a0 * bf2f(u0.y);
                ac2 += a0 * bf2f(u0.z); ac3 += a0 * bf2f(u0.w);
                ac0 += a1 * bf2f(u1.x); ac1 += a1 * bf2f(u1.y);
                ac2 += a1 * bf2f(u1.z); ac3 += a1 * bf2f(u1.w);
                ac0 += a2 * bf2f(u2.x); ac1 += a2 * bf2f(u2.y);
                ac2 += a2 * bf2f(u2.z); ac3 += a2 * bf2f(u2.w);
                ac0 += a3 * bf2f(u3.x); ac1 += a3 * bf2f(u3.y);
                ac2 += a3 * bf2f(u3.z); ac3 += a3 * bf2f(u3.w);
            }
            for (; q < cnt; q++) {
                int b0 = myidx[q];
                float a0 = aA[q];
                ushort4 uv = *(const ushort4*)(hb + b0);
                ac0 += a0 * bf2f(uv.x); ac1 += a0 * bf2f(uv.y);
                ac2 += a0 * bf2f(uv.z); ac3 += a0 * bf2f(uv.w);
            }
        } else {
            const float* aA = myal + selA * AL_ROW;
            const float* aB = myal + selB * AL_ROW;
            int q = 0;
            for (; q + 3 < cnt; q += 4) {
                int b0 = myidx[q], b1 = myidx[q + 1], b2 = myidx[q + 2], b3 = myidx[q + 3];
                float a0 = aA[q], a1 = aA[q + 1], a2 = aA[q + 2], a3 = aA[q + 3];
                float c0 = aB[q], c1 = aB[q + 1], c2 = aB[q + 2], c3 = aB[q + 3];
                ushort4 u0 = *(const ushort4*)(hb + b0);
                ushort4 u1 = *(const ushort4*)(hb + b1);
                ushort4 u2 = *(const ushort4*)(hb + b2);
                ushort4 u3 = *(const ushort4*)(hb + b3);
                ac0 += ((0 < bnd) ? a0 : c0) * bf2f(u0.x);
                ac1 += ((1 < bnd) ? a0 : c0) * bf2f(u0.y);
                ac2 += ((2 < bnd) ? a0 : c0) * bf2f(u0.z);
                ac3 += ((3 < bnd) ? a0 : c0) * bf2f(u0.w);
                ac0 += ((0 < bnd) ? a1 : c1) * bf2f(u1.x);
                ac1 += ((1 < bnd) ? a1 : c1) * bf2f(u1.y);
                ac2 += ((2 < bnd) ? a1 : c1) * bf2f(u1.z);
                ac3 += ((3 < bnd) ? a1 : c1) * bf2f(u1.w);
                ac0 += ((0 < bnd) ? a2 : c2) * bf2f(u2.x);
                ac1 += ((1 < bnd) ? a2 : c2) * bf2f(u2.y);
                ac2 += ((2 < bnd) ? a2 : c2) * bf2f(u2.z);
                ac3 += ((3 < bnd) ? a2 : c2) * bf2f(u2.w);
                ac0 += ((0 < bnd) ? a3 : c3) * bf2f(u3.x);
                ac1 += ((1 < bnd) ? a3 : c3) * bf2f(u3.y);
                ac2 += ((2 < bnd) ? a3 : c3) * bf2f(u3.z);
                ac3 += ((3 < bnd) ? a3 : c3) * bf2f(u3.w);
            }
            for (; q < cnt; q++) {
                int b0 = myidx[q];
                float a0 = aA[q], c0 = aB[q];
                ushort4 uv = *(const ushort4*)(hb + b0);
                ac0 += ((0 < bnd) ? a0 : c0) * bf2f(uv.x);
                ac1 += ((1 < bnd) ? a0 : c0) * bf2f(uv.y);
                ac2 += ((2 < bnd) ? a0 : c0) * bf2f(uv.z);
                ac3 += ((3 < bnd) ? a0 : c0) * bf2f(uv.w);
            }
        }
    }
    float invA = inv_den[(size_t)n * H + hA];
    float invB = inv_den[(size_t)n * H + hB];
    float o0 = ac0 * ((0 < bnd) ? invA : invB) + ((j + 0 < HC) ? bias[j + 0] : 0.f);
    float o1 = ac1 * ((1 < bnd) ? invA : invB) + ((j + 1 < HC) ? bias[j + 1] : 0.f);
    float o2 = ac2 * ((2 < bnd) ? invA : invB) + ((j + 2 < HC) ? bias[j + 2] : 0.f);
    float o3 = ac3 * ((3 < bnd) ? invA : invB) + ((j + 3 < HC) ? bias[j + 3] : 0.f);
    // fused BN stats: per-block LDS reduce, one global atomic per column
    if (cs_out) {
        if (active) {
            int cb = lc << 2;
            atomicAdd(&bn_s[cb + 0], o0); atomicAdd(&bn_q[cb + 0], o0 * o0);
            atomicAdd(&bn_s[cb + 1], o1); atomicAdd(&bn_q[cb + 1], o1 * o1);
            atomicAdd(&bn_s[cb + 2], o2); atomicAdd(&bn_q[cb + 2], o2 * o2);
            atomicAdd(&bn_s[cb + 3], o3); atomicAdd(&bn_q[cb + 3], o3 * o3);
        }
        __syncthreads();
        int sc = 1 << (lcps + 2);                // slab cols
        if (tid < sc) {
            atomicAdd(&cs_out[slab_j + tid], bn_s[tid]);
            atomicAdd(&cq_out[slab_j + tid], bn_q[tid]);
        }
    }
    if (!active) return;
    if (relu) {
        o0 = fmaxf(o0, 0.f); o1 = fmaxf(o1, 0.f);
        o2 = fmaxf(o2, 0.f); o3 = fmaxf(o3, 0.f);
    }
    *(float4*)(out + (size_t)n * opitch + j) = make_float4(o0, o1, o2, o3);
}

// 8 cols/lane TIGHT variant (C%8==0 within slab; used for l2: C=32, hp=128).
// cps=8, G=32, 16B gathers; one alpha row per lane, no selects. Fused BN stats.
__global__ void aggregate_slab8_kernel(const unsigned short* __restrict__ h16,
                                       const float* __restrict__ alpha_t,
                                       const int* __restrict__ off,
                                       const int* __restrict__ csr_src,
                                       const float* __restrict__ bias,
                                       const float* __restrict__ inv_den,
                                       float* __restrict__ out,
                                       int C, int H, int HC, int hp,
                                       int lns, int npr, int nhs, int algstr,
                                       float* __restrict__ cs_out,
                                       float* __restrict__ cq_out,
                                       int relu, int opitch) {
    extern __shared__ char smem[];
    const int cps = 8, G = 32;
    int* sidx = (int*)smem;                      // [G][IDX_STR]
    float* sal = (float*)(smem + (size_t)G * IDX_STR * 4);  // [G][algstr]
    __shared__ int s_maxt;
    __shared__ float bn_s[64];
    __shared__ float bn_q[64];

    int vs = blockIdx.x & 7;
    int nb = blockIdx.x >> 3;
    int slab = vs & ((1 << lns) - 1);
    int rep  = vs >> lns;
    int tid = threadIdx.x;
    int lc = tid & 7;
    int g = tid >> 3;
    int nl = nb * G + g;
    bool active = (nl < npr);
    int n = rep * npr + (active ? nl : 0);

    int slab_j = slab << 6;                      // 64 cols per slab
    int j = slab_j + (lc << 3);
    int hlo = slab_j / C;
    int hd = j / C;                              // single head per lane (C%8==0)
    int sel = hd - hlo; if (sel >= nhs) sel = nhs - 1;
    int hcl = (hd < H) ? hd : H - 1;

    int s = active ? off[n] : 0;
    int e = active ? off[n + 1] : 0;
    int nt = (e - s + AGG_T - 1) / AGG_T;
    int hhi = (slab_j + 63) / C;
    if (hhi > H - 1) hhi = H - 1;
    int nval = hhi - hlo + 1;

    if (tid == 0) s_maxt = 0;
    if (tid < 64) { bn_s[tid] = 0.f; bn_q[tid] = 0.f; }
    __syncthreads();
    if (lc == 0 && active && nt > 0) atomicMax(&s_maxt, nt);
    __syncthreads();
    int maxt = s_maxt;

    int hpb = hp << 1;
    const char* hb = (const char*)(h16 + j);
    int* myidx = sidx + g * IDX_STR;
    float* myal = sal + (size_t)g * algstr;
    float ac0 = 0.f, ac1 = 0.f, ac2 = 0.f, ac3 = 0.f;
    float ac4 = 0.f, ac5 = 0.f, ac6 = 0.f, ac7 = 0.f;

    for (int t = 0; t < maxt; t++) {
        int base = s + t * AGG_T;
        int cnt = e - base;
        if (cnt < 0) cnt = 0;
        if (cnt > AGG_T) cnt = AGG_T;
        __syncthreads();
        for (int q = lc; q < cnt; q += cps)
            myidx[q] = csr_src[base + q] * hpb;
        for (int r = 0; r < nhs; r++) {
            bool hv = (r < nval);
            const float* ar = alpha_t + (size_t)(hlo + r) * ET;
            float* dst = myal + r * AL_ROW;
            for (int q = lc; q < cnt; q += cps)
                dst[q] = hv ? ar[base + q] : 0.f;
        }
        __syncthreads();
        const float* aA = myal + sel * AL_ROW;
        int q = 0;
        for (; q + 1 < cnt; q += 2) {
            int b0 = myidx[q], b1 = myidx[q + 1];
            float a0 = aA[q], a1 = aA[q + 1];
            uint4 u0 = *(const uint4*)(hb + b0);
            uint4 u1 = *(const uint4*)(hb + b1);
            ac0 += a0 * bf_lo(u0.x); ac1 += a0 * bf_hi(u0.x);
            ac2 += a0 * bf_lo(u0.y); ac3 += a0 * bf_hi(u0.y);
            ac4 += a0 * bf_lo(u0.z); ac5 += a0 * bf_hi(u0.z);
            ac6 += a0 * bf_lo(u0.w); ac7 += a0 * bf_hi(u0.w);
            ac0 += a1 * bf_lo(u1.x); ac1 += a1 * bf_hi(u1.x);
            ac2 += a1 * bf_lo(u1.y); ac3 += a1 * bf_hi(u1.y);
            ac4 += a1 * bf_lo(u1.z); ac5 += a1 * bf_hi(u1.z);
            ac6 += a1 * bf_lo(u1.w); ac7 += a1 * bf_hi(u1.w);
        }
        for (; q < cnt; q++) {
            int b0 = myidx[q];
            float a0 = aA[q];
            uint4 uv = *(const uint4*)(hb + b0);
            ac0 += a0 * bf_lo(uv.x); ac1 += a0 * bf_hi(uv.x);
            ac2 += a0 * bf_lo(uv.y); ac3 += a0 * bf_hi(uv.y);
            ac4 += a0 * bf_lo(uv.z); ac5 += a0 * bf_hi(uv.z);
            ac6 += a0 * bf_lo(uv.w); ac7 += a0 * bf_hi(uv.w);
        }
    }
    float inv = inv_den[(size_t)n * H + hcl];
    float o0 = ac0 * inv + ((j + 0 < HC) ? bias[j + 0] : 0.f);
    float o1 = ac1 * inv + ((j + 1 < HC) ? bias[j + 1] : 0.f);
    float o2 = ac2 * inv + ((j + 2 < HC) ? bias[j + 2] : 0.f);
    float o3 = ac3 * inv + ((j + 3 < HC) ? bias[j + 3] : 0.f);
    float o4 = ac4 * inv + ((j + 4 < HC) ? bias[j + 4] : 0.f);
    float o5 = ac5 * inv + ((j + 5 < HC) ? bias[j + 5] : 0.f);
    float o6 = ac6 * inv + ((j + 6 < HC) ? bias[j + 6] : 0.f);
    float o7 = ac7 * inv + ((j + 7 < HC) ? bias[j + 7] : 0.f);
    if (cs_out) {
        if (active) {
            int cb = lc << 3;
            atomicAdd(&bn_s[cb + 0], o0); atomicAdd(&bn_q[cb + 0], o0 * o0);
            atomicAdd(&bn_s[cb + 1], o1); atomicAdd(&bn_q[cb + 1], o1 * o1);
            atomicAdd(&bn_s[cb + 2], o2); atomicAdd(&bn_q[cb + 2], o2 * o2);
            atomicAdd(&bn_s[cb + 3], o3); atomicAdd(&bn_q[cb + 3], o3 * o3);
            atomicAdd(&bn_s[cb + 4], o4); atomicAdd(&bn_q[cb + 4], o4 * o4);
            atomicAdd(&bn_s[cb + 5], o5); atomicAdd(&bn_q[cb + 5], o5 * o5);
            atomicAdd(&bn_s[cb + 6], o6); atomicAdd(&bn_q[cb + 6], o6 * o6);
            atomicAdd(&bn_s[cb + 7], o7); atomicAdd(&bn_q[cb + 7], o7 * o7);
        }
        __syncthreads();
        if (tid < 64) {
            atomicAdd(&cs_out[slab_j + tid], bn_s[tid]);
            atomicAdd(&cq_out[slab_j + tid], bn_q[tid]);
        }
    }
    if (!active) return;
    if (relu) {
        o0 = fmaxf(o0, 0.f); o1 = fmaxf(o1, 0.f); o2 = fmaxf(o2, 0.f); o3 = fmaxf(o3, 0.f);
        o4 = fmaxf(o4, 0.f); o5 = fmaxf(o5, 0.f); o6 = fmaxf(o6, 0.f); o7 = fmaxf(o7, 0.f);
    }
    float* op = out + (size_t)n * opitch + j;
    *(float4*)(op)     = make_float4(o0, o1, o2, o3);
    *(float4*)(op + 4) = make_float4(o4, o5, o6, o7);
}

// scalar fallback (layer 5, HC==1); applies inv_den
__global__ void aggregate_kernel(const float* __restrict__ hfeat,
                                 const float* __restrict__ alpha_t,
                                 const int* __restrict__ off, const int* __restrict__ csr_src,
                                 const float* __restrict__ bias,
                                 const float* __restrict__ inv_den,
                                 float* __restrict__ out, int total) {
    int t = blockIdx.x * blockDim.x + threadIdx.x;
    if (t >= total) return;
    int n = t;
    int s = off[n], e = off[n + 1];
    float acc = 0.f;
    int p = s;
    for (; p + 3 < e; p += 4) {
        acc += alpha_t[p] * hfeat[csr_src[p]]
             + alpha_t[p + 1] * hfeat[csr_src[p + 1]]
             + alpha_t[p + 2] * hfeat[csr_src[p + 2]]
             + alpha_t[p + 3] * hfeat[csr_src[p + 3]];
    }
    for (; p < e; p++) acc += alpha_t[p] * hfeat[csr_src[p]];
    out[n] = acc * inv_den[n] + bias[0];
}

// ---------------- host orchestration ----------------

static inline size_t align_up(size_t v, size_t a) { return (v + a - 1) / a * a; }

extern "C" void kernel_launch(void* const* d_in, const int* in_sizes, int n_in,
                              void* d_out, int out_size, void* d_ws, size_t ws_size,
                              hipStream_t stream) {
    const float* x_in = (const float*)d_in[0];
    const int* ei     = (const int*)d_in[1];
    const float* ew   = (const float*)d_in[2];

    char* pws = (char*)d_ws;
    size_t off_b = 0;
    auto alloc = [&](size_t bytes) -> void* {
        void* rp = pws + off_b;
        off_b = align_up(off_b + bytes, 256);
        return rp;
    };
    float* B0      = (float*)alloc((size_t)NN * 4);            // l5 h vector
    float* B1      = (float*)alloc((size_t)NN * 512 * 4);      // activations (pitched)
    unsigned short* H16 = (unsigned short*)alloc((size_t)NN * 512 * 2);  // padded pitch (64-col slabs)
    float* alpha_t = (float*)alloc((size_t)ET * 5 * 4);        // [H][ET]  (exp, unnormalized)
    unsigned short* Wt_hi = (unsigned short*)alloc((size_t)600 * 512 * 2);
    unsigned short* Wt_lo = (unsigned short*)alloc((size_t)600 * 512 * 2);
    float* al_src  = (float*)alloc((size_t)NN * 5 * 4);
    float* al_dst  = (float*)alloc((size_t)NN * 5 * 4);
    float* inv_den = (float*)alloc((size_t)NN * 5 * 4);
    float* csr_ea  = (float*)alloc((size_t)ET * 4);
    int* rankb     = (int*)alloc((size_t)ET * 4);
    int* csr_src   = (int*)alloc((size_t)ET * 4);
    int* offarr    = (int*)alloc((size_t)(NN + 1) * 4);
    float* we_dot  = (float*)alloc(40 * 4);
    // zero-region: esum + cnt + 3x colsum + 3x colsumsq (one memset)
    float* esum    = (float*)alloc(4);
    int* cnt       = (int*)alloc((size_t)NN * 4);
    float* colsum_all   = (float*)alloc(3 * 512 * 4);
    float* colsumsq_all = (float*)alloc(3 * 512 * 4);
    char* zero_end = pws + off_b;
    (void)ws_size; (void)n_in; (void)in_sizes; (void)out_size;

    int Kp[5], Np[5], hp[5];
    size_t wtoff[5];
    size_t acc_off = 0;
    for (int l = 0; l < 5; l++) {
        int K = g_cfg[l].cin, HC = g_cfg[l].C * g_cfg[l].H;
        Kp[l] = (K + 31) / 32 * 32;
        Np[l] = (HC + 127) / 128 * 128;
        hp[l] = (HC >= 64) ? ((HC + 63) / 64 * 64) : ((HC + 7) / 8 * 8);
        wtoff[l] = acc_off;
        acc_off += (size_t)Kp[l] * Np[l];
    }

    PrepArgs pa;
    for (int l = 0; l < 5; l++) {
        pa.W[l]  = (const float*)d_in[3 + l * 6 + 0];
        pa.We[l] = (const float*)d_in[3 + l * 6 + 3];
        pa.ae[l] = (const float*)d_in[3 + l * 6 + 4];
        pa.bh[l] = Wt_hi + wtoff[l];
        pa.bl[l] = Wt_lo + wtoff[l];
        pa.K[l] = g_cfg[l].cin;
        pa.N[l] = g_cfg[l].C * g_cfg[l].H;
        pa.Kp[l] = Kp[l];
        pa.Np[l] = Np[l];
        pa.C[l] = g_cfg[l].C;
        pa.H[l] = g_cfg[l].H;
    }
    pa.wedot = we_dot;

    hipMemsetAsync(esum, 0, (size_t)(zero_end - (char*)esum), stream);
    int ebl = EBLK;
    prep_fused_kernel<<<ebl + 256 + 1280, 256, 0, stream>>>(ei, rankb, cnt, ew, esum, pa);
    scan_kernel<<<1, 1024, 0, stream>>>(cnt, offarr);
    fill_kernel<<<ebl, 256, 0, stream>>>(ei, rankb, ew, esum, offarr, csr_src, csr_ea);

    for (int l = 0; l < 5; l++) {
        const LayerCfg& cf = g_cfg[l];
        int H = cf.H, C = cf.C;
        int HC = H * C;
        const float* a_s = (const float*)d_in[3 + l * 6 + 1];
        const float* a_d = (const float*)d_in[3 + l * 6 + 2];
        const float* b   = (const float*)d_in[3 + l * 6 + 5];

        const float* X = (l == 0) ? x_in : B1;
        float* outbuf = (l == 4) ? (float*)d_out : B1;
        int opitch = (l == 4) ? 1 : Kp[l + 1];
        int NH = NN * H;
        int alblocks = (NN * 64 + 255) / 256;

        if (l == 4) {
            gemv_l5_kernel<<<(NN + 255) / 256, 256, 0, stream>>>(
                X, pa.W[4], a_s, a_d, B0, al_src, al_dst);
        } else {
            const float* cs = (l >= 1) ? colsum_all + (l - 1) * 512 : nullptr;
            const float* cq = (l >= 1) ? colsumsq_all + (l - 1) * 512 : nullptr;
            const float* gg = (l >= 1) ? (const float*)d_in[33 + (l - 1) * 2 + 0] : nullptr;
            const float* bb = (l >= 1) ? (const float*)d_in[33 + (l - 1) * 2 + 1] : nullptr;
            int Din = (l >= 1) ? g_cfg[l - 1].C * g_cfg[l - 1].H : 0;
            dim3 ggrid(Np[l] / GBNT, (NN + GBM - 1) / GBM);
            gemm_split_kernel<<<ggrid, 256, 0, stream>>>(X, Wt_hi + wtoff[l], Wt_lo + wtoff[l],
                                                         nullptr, H16,
                                                         NN, Kp[l], hp[l], cs, cq, gg, bb, Din);
            al_wave_h16_kernel<<<alblocks, 256, 0, stream>>>(H16, a_s, a_d, al_src, al_dst, H, C, hp[l]);
        }

        attn_kernel<<<(NH + 255) / 256, 256, 0, stream>>>(al_src, al_dst, csr_src, csr_ea,
                                                          we_dot + l * 8, offarr, alpha_t,
                                                          inv_den, H, NH);

        // fused BN stats target (outputs of l=0,1,2 feed next layer's BN)
        float* csO = (l < 3) ? colsum_all + l * 512 : nullptr;
        float* cqO = (l < 3) ? colsumsq_all + l * 512 : nullptr;

        if (l == 4) {
            aggregate_kernel<<<(NN + 255) / 256, 256, 0, stream>>>(
                B0, alpha_t, offarr, csr_src, b, inv_den, outbuf, NN);
        } else if (l == 2) {
            // 8-col tight variant: C=32 (C%8==0), hp=128 -> 2 slabs, dup=4
            int nslabs = hp[l] / 64;                          // 2
            int lns = (nslabs == 2) ? 1 : 0;
            int dup = 8 / nslabs;
            int npr = NN / dup;
            int G = 32;
            int gx = 8 * ((npr + G - 1) / G);
            int nhs = 1;
            for (int sbi = 0; sbi < nslabs; sbi++) {
                int j0 = sbi * 64;
                int span = (j0 + 63) / C - j0 / C + 1;
                if (span > nhs) nhs = span;
            }
            int algstr = nhs * AL_ROW + 4;
            size_t smem = (size_t)G * IDX_STR * 4 + (size_t)G * algstr * 4;
            aggregate_slab8_kernel<<<gx, 256, smem, stream>>>(
                H16, alpha_t, offarr, csr_src, b, inv_den, outbuf,
                C, H, HC, hp[l], lns, npr, nhs, algstr, csO, cqO, 0, opitch);
        } else {
            int cps = (hp[l] >= 64) ? 16 : 8;
            int lcps = (cps == 16) ? 4 : 3;
            int slabcols = cps * 4;
            int nslabs = hp[l] / slabcols;
            int lns = (nslabs == 8) ? 3 : (nslabs == 4) ? 2 : (nslabs == 2) ? 1 : 0;
            int dup = 8 / nslabs;
            int npr = NN / dup;           // 30000 divisible by 1,2,4,8
            int G = 256 / cps;
            int gx = 8 * ((npr + G - 1) / G);
            int nhs = 1;
            for (int sbi = 0; sbi < nslabs; sbi++) {
                int j0 = sbi * slabcols;
                int span = (j0 + slabcols - 1) / C - j0 / C + 1;
                if (span > nhs) nhs = span;
            }
            int algstr = nhs * AL_ROW + 4;   // bank-staggered group stride (floats)
            int tight = ((C & 3) == 0) ? 1 : 0;
            size_t smem = (size_t)G * IDX_STR * 4 + (size_t)G * algstr * 4;
            aggregate_slab_lds_kernel<<<gx, 256, smem, stream>>>(
                H16, alpha_t, offarr, csr_src, b, inv_den, outbuf,
                C, H, HC, hp[l], lns, lcps, npr, nhs, algstr, tight,
                csO, cqO, (l == 3) ? 1 : 0, opitch);
        }
    }
}

// Round 9
// 745.708 us; speedup vs baseline: 1.1689x; 1.1689x over previous
//
#include <hip/hip_runtime.h>
#include <hip/hip_bf16.h>
#include <math.h>

// ---------------- problem constants ----------------
#define NN 30000
#define EE 480000
#define ET (EE + NN)   // edges + self loops = 510000
#define NEG_SLOPE 0.2f
#define BN_EPS 1e-5f

struct LayerCfg { int cin, C, H; };
static const LayerCfg g_cfg[5] = {
    {128, 100, 5}, {500, 50, 5}, {250, 32, 4}, {128, 8, 4}, {32, 1, 1}
};

typedef short short8 __attribute__((ext_vector_type(8)));
typedef float f32x4 __attribute__((ext_vector_type(4)));

__device__ __forceinline__ unsigned short f2bf(float f) {
    unsigned int u = __builtin_bit_cast(unsigned int, f);
    u = (u + 0x7FFFu + ((u >> 16) & 1u)) >> 16;
    return (unsigned short)u;
}
__device__ __forceinline__ float bf2f(unsigned short h) {
    unsigned int u = ((unsigned int)h) << 16;
    return __builtin_bit_cast(float, u);
}

// ---------------- all-layer weight prep args ----------------

struct PrepArgs {
    const float* W[5];
    const float* We[5];
    const float* ae[5];
    unsigned short* bh[5];
    unsigned short* bl[5];
    float* wedot;            // out: [5][8]
    int K[5], N[5], Kp[5], Np[5], C[5], H[5];
};

// fused independent prep: build_edges histogram + edge-weight sum + weight transpose.
static const int EBLK = (ET + 255) / 256;

__global__ void prep_fused_kernel(const int* __restrict__ ei, int* __restrict__ rank,
                                  int* __restrict__ cnt, const float* __restrict__ ew,
                                  float* __restrict__ esum, PrepArgs a) {
    __shared__ float sdata[256];
    __shared__ float tile[32][33];
    int b = blockIdx.x;
    int tid = threadIdx.x;

    if (b < EBLK) {
        int e = b * 256 + tid;
        if (e < ET) {
            int d = (e < EE) ? ei[EE + e] : (e - EE);
            rank[e] = atomicAdd(&cnt[d], 1);
        }
        return;
    }
    b -= EBLK;
    if (b < 256) {
        float s = 0.f;
        for (int i = b * 256 + tid; i < EE; i += 65536)
            s += ew[i];
        sdata[tid] = s;
        __syncthreads();
        for (int off = 128; off > 0; off >>= 1) {
            if (tid < off) sdata[tid] += sdata[tid + off];
            __syncthreads();
        }
        if (tid == 0) atomicAdd(esum, sdata[0]);
        return;
    }
    b -= 256;
    int bx = b & 15, by = (b >> 4) & 15, bz = b >> 8;
    int l = bz;
    int tx = tid & 31, ty = tid >> 5;      // 32 x 8
    if (bx == 0 && by == 0 && ty == 0 && tx < 8) {
        int hd = tx;
        if (hd < a.H[l]) {
            int C = a.C[l];
            const float* We = a.We[l] + hd * C;
            const float* ae = a.ae[l] + hd * C;
            float s = 0.f;
            for (int c = 0; c < C; c++) s += We[c] * ae[c];
            a.wedot[l * 8 + hd] = s;
        }
    }
    int Kp = a.Kp[l], Np = a.Np[l], K = a.K[l], N = a.N[l];
    int kb = bx * 32, nb = by * 32;
    if (kb >= Kp || nb >= Np) return;
    const float* B = a.W[l];
    unsigned short* Bth = a.bh[l];
    unsigned short* Btl = a.bl[l];
#pragma unroll
    for (int i = 0; i < 4; i++) {
        int k = kb + ty + i * 8, n = nb + tx;
        tile[ty + i * 8][tx] = (k < K && n < N) ? B[(size_t)k * N + n] : 0.f;
    }
    __syncthreads();
#pragma unroll
    for (int i = 0; i < 4; i++) {
        int n = nb + ty + i * 8, k = kb + tx;
        if (n < Np && k < Kp) {
            float v = tile[tx][ty + i * 8];
            unsigned short hi = f2bf(v);
            unsigned short lo = f2bf(v - bf2f(hi));
            size_t idx = (size_t)n * Kp + k;
            Bth[idx] = hi;
            Btl[idx] = lo;
        }
    }
}

// exclusive prefix over cnt -> off
__global__ void scan_kernel(const int* __restrict__ cnt, int* __restrict__ off) {
    __shared__ int lsum[1024];
    const int T = 1024;
    int t = threadIdx.x;
    int chunk = (NN + T - 1) / T;
    int base = t * chunk;
    int end = min(NN, base + chunk);
    int s = 0;
    for (int i = base; i < end; i++) s += cnt[i];
    lsum[t] = s;
    __syncthreads();
    for (int d = 1; d < T; d <<= 1) {
        int v = (t >= d) ? lsum[t - d] : 0;
        __syncthreads();
        lsum[t] += v;
        __syncthreads();
    }
    int run = (t == 0) ? 0 : lsum[t - 1];
    for (int i = base; i < end; i++) {
        off[i] = run;
        run += cnt[i];
    }
    if (t == 0) off[NN] = ET;
}

// scatter edges to CSR order via precomputed rank — NO atomics
__global__ void fill_kernel(const int* __restrict__ ei, const int* __restrict__ rank,
                            const float* __restrict__ ew, const float* __restrict__ esum,
                            const int* __restrict__ off,
                            int* __restrict__ csr_src, float* __restrict__ csr_ea) {
    int e = blockIdx.x * blockDim.x + threadIdx.x;
    if (e >= ET) return;
    int sv, d;
    if (e < EE) { sv = ei[e]; d = ei[EE + e]; }
    else        { sv = e - EE; d = e - EE; }
    int p = off[d] + rank[e];
    csr_src[p] = sv;
    csr_ea[p]  = (e < EE) ? ew[e] : esum[0] * (1.0f / (float)EE);
}

// ---------------- split-bf16 MFMA GEMM with optional fused BN+ReLU on A ----------------
#define GBM 128
#define GBNT 128
#define GBK 32
#define ASTR 36
__global__ __launch_bounds__(256) void gemm_split_kernel(const float* __restrict__ A,
                                                         const unsigned short* __restrict__ Bt_hi,
                                                         const unsigned short* __restrict__ Bt_lo,
                                                         float* __restrict__ Cm,
                                                         unsigned short* __restrict__ Ch16,
                                                         int M, int Kp, int Nc,
                                                         const float* __restrict__ colsum,
                                                         const float* __restrict__ colsumsq,
                                                         const float* __restrict__ g,
                                                         const float* __restrict__ beta,
                                                         int D) {
    __shared__ short AsH[GBM * ASTR];
    __shared__ short AsL[GBM * ASTR];
    __shared__ short BsH[GBNT * ASTR];
    __shared__ short BsL[GBNT * ASTR];
    __shared__ float sscale[512];
    __shared__ float sshift[512];
    int tid = threadIdx.x;
    bool bn = (colsum != nullptr);
    if (bn) {
        for (int c = tid; c < Kp; c += 256) {
            float sc = 0.f, sh = 0.f;
            if (c < D) {
                float mu = colsum[c] * (1.0f / (float)NN);
                float var = colsumsq[c] * (1.0f / (float)NN) - mu * mu;
                sc = g[c] * rsqrtf(var + BN_EPS);
                sh = beta[c] - mu * sc;
            }
            sscale[c] = sc;
            sshift[c] = sh;
        }
        __syncthreads();
    }
    int wave = tid >> 6, lane = tid & 63;
    int q = lane >> 4, r = lane & 15;
    int m0 = blockIdx.y * GBM, n0 = blockIdx.x * GBNT;
    int wm = (wave & 1) * 64, wn = (wave >> 1) * 64;
    f32x4 acc[4][4];
#pragma unroll
    for (int i = 0; i < 4; i++)
#pragma unroll
        for (int j = 0; j < 4; j++) acc[i][j] = (f32x4)(0.f);

    int arow2 = tid >> 1;
    int acol2 = (tid & 1) * 16;
    int brow = tid >> 2;
    int bcol = (tid & 3) * 8;

    int ksteps = Kp / GBK;
    for (int ks = 0; ks < ksteps; ks++) {
        int k0 = ks * GBK;
        {
            int m = m0 + arow2;
            float v[16];
            if (m < M) {
                const float* Ap = A + (size_t)m * Kp + k0 + acol2;
                float4 f0 = *(const float4*)(Ap);
                float4 f1 = *(const float4*)(Ap + 4);
                float4 f2 = *(const float4*)(Ap + 8);
                float4 f3 = *(const float4*)(Ap + 12);
                v[0]=f0.x; v[1]=f0.y; v[2]=f0.z; v[3]=f0.w;
                v[4]=f1.x; v[5]=f1.y; v[6]=f1.z; v[7]=f1.w;
                v[8]=f2.x; v[9]=f2.y; v[10]=f2.z; v[11]=f2.w;
                v[12]=f3.x; v[13]=f3.y; v[14]=f3.z; v[15]=f3.w;
                if (bn) {
                    int cb = k0 + acol2;
#pragma unroll
                    for (int i = 0; i < 16; i++)
                        v[i] = fmaxf(v[i] * sscale[cb + i] + sshift[cb + i], 0.f);
                }
            } else {
#pragma unroll
                for (int i = 0; i < 16; i++) v[i] = 0.f;
            }
#pragma unroll
            for (int i = 0; i < 16; i++) {
                unsigned short hi = f2bf(v[i]);
                unsigned short lo = f2bf(v[i] - bf2f(hi));
                AsH[arow2 * ASTR + acol2 + i] = (short)hi;
                AsL[arow2 * ASTR + acol2 + i] = (short)lo;
            }
        }
#pragma unroll
        for (int p = 0; p < 2; p++) {
            int row = p * 64 + brow;
            size_t gidx = (size_t)(n0 + row) * Kp + k0 + bcol;
            *((uint4*)(BsH + row * ASTR + bcol)) = *((const uint4*)(Bt_hi + gidx));
            *((uint4*)(BsL + row * ASTR + bcol)) = *((const uint4*)(Bt_lo + gidx));
        }
        __syncthreads();
        short8 ah[4], al[4], bh[4], bl[4];
#pragma unroll
        for (int i = 0; i < 4; i++) {
            ah[i] = *((const short8*)(AsH + (wm + i * 16 + r) * ASTR + q * 8));
            al[i] = *((const short8*)(AsL + (wm + i * 16 + r) * ASTR + q * 8));
        }
#pragma unroll
        for (int j = 0; j < 4; j++) {
            bh[j] = *((const short8*)(BsH + (wn + j * 16 + r) * ASTR + q * 8));
            bl[j] = *((const short8*)(BsL + (wn + j * 16 + r) * ASTR + q * 8));
        }
#pragma unroll
        for (int i = 0; i < 4; i++)
#pragma unroll
            for (int j = 0; j < 4; j++) {
                acc[i][j] = __builtin_amdgcn_mfma_f32_16x16x32_bf16(ah[i], bh[j], acc[i][j], 0, 0, 0);
                acc[i][j] = __builtin_amdgcn_mfma_f32_16x16x32_bf16(ah[i], bl[j], acc[i][j], 0, 0, 0);
                acc[i][j] = __builtin_amdgcn_mfma_f32_16x16x32_bf16(al[i], bh[j], acc[i][j], 0, 0, 0);
            }
        __syncthreads();
    }
#pragma unroll
    for (int i = 0; i < 4; i++) {
#pragma unroll
        for (int j = 0; j < 4; j++) {
#pragma unroll
            for (int reg = 0; reg < 4; reg++) {
                int mrow = m0 + wm + i * 16 + q * 4 + reg;
                int ncol = n0 + wn + j * 16 + r;
                if (mrow < M && ncol < Nc) {
                    float val = acc[i][j][reg];
                    if (Cm)   Cm[(size_t)mrow * Nc + ncol] = val;
                    if (Ch16) Ch16[(size_t)mrow * Nc + ncol] = f2bf(val);
                }
            }
        }
    }
}

// layer-5 fused GEMV
__global__ void gemv_l5_kernel(const float* __restrict__ X, const float* __restrict__ W,
                               const float* __restrict__ a_s, const float* __restrict__ a_d,
                               float* __restrict__ h, float* __restrict__ al_src,
                               float* __restrict__ al_dst) {
    __shared__ float w[32];
    if (threadIdx.x < 32) w[threadIdx.x] = W[threadIdx.x];
    __syncthreads();
    int n = blockIdx.x * blockDim.x + threadIdx.x;
    if (n >= NN) return;
    const float* row = X + (size_t)n * 32;
    float s = 0.f;
#pragma unroll
    for (int i = 0; i < 8; i++) {
        float4 f = *(const float4*)(row + i * 4);
        s += f.x * w[i * 4] + f.y * w[i * 4 + 1] + f.z * w[i * 4 + 2] + f.w * w[i * 4 + 3];
    }
    h[n] = s;
    al_src[n] = s * a_s[0];
    al_dst[n] = s * a_d[0];
}

// wave-per-node attention dots, bf16 h (layers 1-4); HCp = padded row pitch
__global__ void al_wave_h16_kernel(const unsigned short* __restrict__ h16,
                                   const float* __restrict__ a_s,
                                   const float* __restrict__ a_d,
                                   float* __restrict__ al_src, float* __restrict__ al_dst,
                                   int H, int C, int HCp) {
    int w = (blockIdx.x * blockDim.x + threadIdx.x) >> 6;
    int lane = threadIdx.x & 63;
    if (w >= NN) return;
    const unsigned short* row = h16 + (size_t)w * HCp;
    float s1[5] = {0.f, 0.f, 0.f, 0.f, 0.f};
    float s2[5] = {0.f, 0.f, 0.f, 0.f, 0.f};
#pragma unroll
    for (int hd = 0; hd < 5; hd++) {
        if (hd >= H) break;
        int base = hd * C;
        for (int c = lane * 2; c < C; c += 128) {
            unsigned int u = *(const unsigned int*)(row + base + c);
            float v0 = bf2f((unsigned short)(u & 0xffffu));
            float v1 = bf2f((unsigned short)(u >> 16));
            s1[hd] += v0 * a_s[base + c] + v1 * a_s[base + c + 1];
            s2[hd] += v0 * a_d[base + c] + v1 * a_d[base + c + 1];
        }
    }
#pragma unroll
    for (int hd = 0; hd < 5; hd++) {
        if (hd >= H) break;
#pragma unroll
        for (int off = 32; off > 0; off >>= 1) {
            s1[hd] += __shfl_xor(s1[hd], off, 64);
            s2[hd] += __shfl_xor(s2[hd], off, 64);
        }
    }
    if (lane == 0) {
#pragma unroll
        for (int hd = 0; hd < 5; hd++) {
            if (hd >= H) break;
            al_src[(size_t)w * H + hd] = s1[hd];
            al_dst[(size_t)w * H + hd] = s2[hd];
        }
    }
}

// SINGLE-PASS attn: writes UNNORMALIZED exp(logit) to alpha_t and 1/den to
// inv_den[n*H+hd]; the aggregate multiplies by inv_den in its epilogue.
__global__ void attn_kernel(const float* __restrict__ al_src,
                            const float* __restrict__ al_dst,
                            const int* __restrict__ csr_src,
                            const float* __restrict__ csr_ea,
                            const float* __restrict__ we_dot,
                            const int* __restrict__ off,
                            float* __restrict__ alpha_t,
                            float* __restrict__ inv_den, int H, int NH) {
    int t = blockIdx.x * blockDim.x + threadIdx.x;
    if (t >= NH) return;
    int n = t / H, hd = t - n * H;
    int s = off[n], e = off[n + 1];
    float ad = al_dst[(size_t)n * H + hd];
    float wd = we_dot[hd];
    float* arow = alpha_t + (size_t)hd * ET;
    float den = 0.f;
    int p = s;
    for (; p + 3 < e; p += 4) {
        int s0 = csr_src[p], s1 = csr_src[p + 1], s2 = csr_src[p + 2], s3 = csr_src[p + 3];
        float w0 = csr_ea[p], w1 = csr_ea[p + 1], w2 = csr_ea[p + 2], w3 = csr_ea[p + 3];
        float l0 = al_src[(size_t)s0 * H + hd] + ad + w0 * wd;
        float l1 = al_src[(size_t)s1 * H + hd] + ad + w1 * wd;
        float l2 = al_src[(size_t)s2 * H + hd] + ad + w2 * wd;
        float l3 = al_src[(size_t)s3 * H + hd] + ad + w3 * wd;
        l0 = (l0 >= 0.f) ? l0 : NEG_SLOPE * l0;
        l1 = (l1 >= 0.f) ? l1 : NEG_SLOPE * l1;
        l2 = (l2 >= 0.f) ? l2 : NEG_SLOPE * l2;
        l3 = (l3 >= 0.f) ? l3 : NEG_SLOPE * l3;
        float e0 = __expf(l0), e1 = __expf(l1), e2 = __expf(l2), e3 = __expf(l3);
        arow[p] = e0; arow[p + 1] = e1; arow[p + 2] = e2; arow[p + 3] = e3;
        den += e0 + e1 + e2 + e3;
    }
    for (; p < e; p++) {
        float lg = al_src[(size_t)csr_src[p] * H + hd] + ad + csr_ea[p] * wd;
        lg = (lg >= 0.f) ? lg : NEG_SLOPE * lg;
        float ex = __expf(lg);
        arow[p] = ex;
        den += ex;
    }
    inv_den[t] = 1.f / fmaxf(den, 1e-16f);
}

// ---------------- slab-partitioned gather aggregate, LDS-staged edges ----------------
// Slab pinned to an XCD via blockIdx&7 (FETCH 262->82MB verified). csr_src (as
// PRE-MULTIPLIED byte offsets) + the slab's nhs alpha head-rows staged in LDS
// with bank-conflict-free padded strides (conflicts 1.13e7->3.8e5 verified).
// Stage loops bounded by cnt; per-LAYER `tight` specialization (C%4==0).
// NOTE r8 lesson: do NOT fuse BN column stats here — the per-block LDS-atomic
// reduce + ~2M global atomics cost 2.5x the kernel (82.7->209us, WRITE +7.5MB);
// the standalone 512-block bn_stats pass is far cheaper.
#define AGG_T 64
#define IDX_STR 68
#define AL_ROW 68
__global__ void aggregate_slab_lds_kernel(const unsigned short* __restrict__ h16,
                                          const float* __restrict__ alpha_t,
                                          const int* __restrict__ off,
                                          const int* __restrict__ csr_src,
                                          const float* __restrict__ bias,
                                          const float* __restrict__ inv_den,
                                          float* __restrict__ out,
                                          int C, int H, int HC, int hp,
                                          int lns, int lcps, int npr, int nhs,
                                          int algstr, int tight, int relu, int opitch) {
    extern __shared__ char smem[];
    int cps = 1 << lcps;
    int G = 256 >> lcps;                         // nodes per block
    int* sidx = (int*)smem;                      // [G][IDX_STR]
    float* sal = (float*)(smem + (size_t)G * IDX_STR * 4);  // [G][algstr]
    __shared__ int s_maxt;

    int vs = blockIdx.x & 7;
    int nb = blockIdx.x >> 3;
    int slab = vs & ((1 << lns) - 1);
    int rep  = vs >> lns;
    int tid = threadIdx.x;
    int lc = tid & (cps - 1);
    int g = tid >> lcps;                         // node slot within block
    int nl = nb * G + g;
    bool active = (nl < npr);
    int n = rep * npr + (active ? nl : 0);

    int slab_j = slab << (lcps + 2);
    int j = slab_j + (lc << 2);
    int hlo = slab_j / C;
    int hhi = (slab_j + (cps << 2) - 1) / C;
    if (hhi > H - 1) hhi = H - 1;
    int nval = hhi - hlo + 1;                    // valid alpha rows staged

    int hdA = j / C;
    int hdB = (j + 3) / C;
    int bnd = (hdA + 1) * C - j;
    bnd = (bnd > 4) ? 4 : bnd;
    int selA = hdA - hlo; if (selA >= nhs) selA = nhs - 1;
    int selB = hdB - hlo; if (selB >= nhs) selB = nhs - 1;
    int hA = (hdA < H) ? hdA : H - 1;            // clamped heads for inv_den
    int hB = (hdB < H) ? hdB : H - 1;

    int s = active ? off[n] : 0;
    int e = active ? off[n + 1] : 0;
    int nt = (e - s + AGG_T - 1) / AGG_T;

    if (tid == 0) s_maxt = 0;
    __syncthreads();
    if (lc == 0 && active && nt > 0) atomicMax(&s_maxt, nt);
    __syncthreads();
    int maxt = s_maxt;

    int hpb = hp << 1;                           // bytes per h16 row
    const char* hb = (const char*)(h16 + j);
    int* myidx = sidx + g * IDX_STR;
    float* myal = sal + (size_t)g * algstr;
    float ac0 = 0.f, ac1 = 0.f, ac2 = 0.f, ac3 = 0.f;

    for (int t = 0; t < maxt; t++) {
        int base = s + t * AGG_T;
        int cnt = e - base;
        if (cnt < 0) cnt = 0;
        if (cnt > AGG_T) cnt = AGG_T;
        __syncthreads();   // protect prior-iteration LDS reads before overwrite
        // stage ONLY cnt slots (was AGG_T: ~73% wasted at mean deg 17)
        for (int q = lc; q < cnt; q += cps)
            myidx[q] = csr_src[base + q] * hpb;
        for (int r = 0; r < nhs; r++) {
            bool hv = (r < nval);
            const float* ar = alpha_t + (size_t)(hlo + r) * ET;
            float* dst = myal + r * AL_ROW;
            for (int q = lc; q < cnt; q += cps)
                dst[q] = hv ? ar[base + q] : 0.f;
        }
        __syncthreads();
        if (tight) {
            // C%4==0: chunk never straddles a head boundary
            const float* aA = myal + selA * AL_ROW;
            int q = 0;
            for (; q + 3 < cnt; q += 4) {
                int b0 = myidx[q], b1 = myidx[q + 1], b2 = myidx[q + 2], b3 = myidx[q + 3];
                float a0 = aA[q], a1 = aA[q + 1], a2 = aA[q + 2], a3 = aA[q + 3];
                ushort4 u0 = *(const ushort4*)(hb + b0);
                ushort4 u1 = *(const ushort4*)(hb + b1);
                ushort4 u2 = *(const ushort4*)(hb + b2);
                ushort4 u3 = *(const ushort4*)(hb + b3);
                ac0 += a0 * bf2f(u0.x); ac1 += a0 * bf2f(u0.y);
                ac2 += a0 * bf2f(u0.z); ac3 += a0 * bf2f(u0.w);
                ac0 += a1 * bf2f(u1.x); ac1 += a1 * bf2f(u1.y);
                ac2 += a1 * bf2f(u1.z); ac3 += a1 * bf2f(u1.w);
                ac0 += a2 * bf2f(u2.x); ac1 += a2 * bf2f(u2.y);
                ac2 += a2 * bf2f(u2.z); ac3 += a2 * bf2f(u2.w);
                ac0 += a3 * bf2f(u3.x); ac1 += a3 * bf2f(u3.y);
                ac2 += a3 * bf2f(u3.z); ac3 += a3 * bf2f(u3.w);
            }
            for (; q < cnt; q++) {
                int b0 = myidx[q];
                float a0 = aA[q];
                ushort4 uv = *(const ushort4*)(hb + b0);
                ac0 += a0 * bf2f(uv.x); ac1 += a0 * bf2f(uv.y);
                ac2 += a0 * bf2f(uv.z); ac3 += a0 * bf2f(uv.w);
            }
        } else {
            const float* aA = myal + selA * AL_ROW;
            const float* aB = myal + selB * AL_ROW;
            int q = 0;
            for (; q + 3 < cnt; q += 4) {
                int b0 = myidx[q], b1 = myidx[q + 1], b2 = myidx[q + 2], b3 = myidx[q + 3];
                float a0 = aA[q], a1 = aA[q + 1], a2 = aA[q + 2], a3 = aA[q + 3];
                float c0 = aB[q], c1 = aB[q + 1], c2 = aB[q + 2], c3 = aB[q + 3];
                ushort4 u0 = *(const ushort4*)(hb + b0);
                ushort4 u1 = *(const ushort4*)(hb + b1);
                ushort4 u2 = *(const ushort4*)(hb + b2);
                ushort4 u3 = *(const ushort4*)(hb + b3);
                ac0 += ((0 < bnd) ? a0 : c0) * bf2f(u0.x);
                ac1 += ((1 < bnd) ? a0 : c0) * bf2f(u0.y);
                ac2 += ((2 < bnd) ? a0 : c0) * bf2f(u0.z);
                ac3 += ((3 < bnd) ? a0 : c0) * bf2f(u0.w);
                ac0 += ((0 < bnd) ? a1 : c1) * bf2f(u1.x);
                ac1 += ((1 < bnd) ? a1 : c1) * bf2f(u1.y);
                ac2 += ((2 < bnd) ? a1 : c1) * bf2f(u1.z);
                ac3 += ((3 < bnd) ? a1 : c1) * bf2f(u1.w);
                ac0 += ((0 < bnd) ? a2 : c2) * bf2f(u2.x);
                ac1 += ((1 < bnd) ? a2 : c2) * bf2f(u2.y);
                ac2 += ((2 < bnd) ? a2 : c2) * bf2f(u2.z);
                ac3 += ((3 < bnd) ? a2 : c2) * bf2f(u2.w);
                ac0 += ((0 < bnd) ? a3 : c3) * bf2f(u3.x);
                ac1 += ((1 < bnd) ? a3 : c3) * bf2f(u3.y);
                ac2 += ((2 < bnd) ? a3 : c3) * bf2f(u3.z);
                ac3 += ((3 < bnd) ? a3 : c3) * bf2f(u3.w);
            }
            for (; q < cnt; q++) {
                int b0 = myidx[q];
                float a0 = aA[q], c0 = aB[q];
                ushort4 uv = *(const ushort4*)(hb + b0);
                ac0 += ((0 < bnd) ? a0 : c0) * bf2f(uv.x);
                ac1 += ((1 < bnd) ? a0 : c0) * bf2f(uv.y);
                ac2 += ((2 < bnd) ? a0 : c0) * bf2f(uv.z);
                ac3 += ((3 < bnd) ? a0 : c0) * bf2f(uv.w);
            }
        }
    }
    if (!active) return;
    float invA = inv_den[(size_t)n * H + hA];
    float invB = inv_den[(size_t)n * H + hB];
    // pad heads were staged as zero -> acc already 0 there; bias 0 beyond HC
    float o0 = ac0 * ((0 < bnd) ? invA : invB) + ((j + 0 < HC) ? bias[j + 0] : 0.f);
    float o1 = ac1 * ((1 < bnd) ? invA : invB) + ((j + 1 < HC) ? bias[j + 1] : 0.f);
    float o2 = ac2 * ((2 < bnd) ? invA : invB) + ((j + 2 < HC) ? bias[j + 2] : 0.f);
    float o3 = ac3 * ((3 < bnd) ? invA : invB) + ((j + 3 < HC) ? bias[j + 3] : 0.f);
    if (relu) {
        o0 = fmaxf(o0, 0.f); o1 = fmaxf(o1, 0.f);
        o2 = fmaxf(o2, 0.f); o3 = fmaxf(o3, 0.f);
    }
    *(float4*)(out + (size_t)n * opitch + j) = make_float4(o0, o1, o2, o3);
}

// scalar fallback (layer 5, HC==1); applies inv_den
__global__ void aggregate_kernel(const float* __restrict__ hfeat,
                                 const float* __restrict__ alpha_t,
                                 const int* __restrict__ off, const int* __restrict__ csr_src,
                                 const float* __restrict__ bias,
                                 const float* __restrict__ inv_den,
                                 float* __restrict__ out, int total) {
    int t = blockIdx.x * blockDim.x + threadIdx.x;
    if (t >= total) return;
    int n = t;
    int s = off[n], e = off[n + 1];
    float acc = 0.f;
    int p = s;
    for (; p + 3 < e; p += 4) {
        acc += alpha_t[p] * hfeat[csr_src[p]]
             + alpha_t[p + 1] * hfeat[csr_src[p + 1]]
             + alpha_t[p + 2] * hfeat[csr_src[p + 2]]
             + alpha_t[p + 3] * hfeat[csr_src[p + 3]];
    }
    for (; p < e; p++) acc += alpha_t[p] * hfeat[csr_src[p]];
    out[n] = acc * inv_den[n] + bias[0];
}

// ---------------- BN stats (pitched); 512 blocks (128 was a 5x regression: latency-bound) ----------------

__global__ void bn_stats_kernel(const float* __restrict__ x, float* __restrict__ colsum,
                                float* __restrict__ colsumsq, int D, int pitch) {
    int rows_per_block = (NN + gridDim.x - 1) / gridDim.x;
    int r0 = blockIdx.x * rows_per_block;
    int r1 = min(NN, r0 + rows_per_block);
    int c0 = threadIdx.x;
    int c1 = threadIdx.x + 256;
    float s0 = 0.f, q0 = 0.f, s1 = 0.f, q1 = 0.f;
    for (int r = r0; r < r1; r++) {
        const float* row = x + (size_t)r * pitch;
        if (c0 < D) { float v = row[c0]; s0 += v; q0 += v * v; }
        if (c1 < D) { float v = row[c1]; s1 += v; q1 += v * v; }
    }
    if (c0 < D) { atomicAdd(&colsum[c0], s0); atomicAdd(&colsumsq[c0], q0); }
    if (c1 < D) { atomicAdd(&colsum[c1], s1); atomicAdd(&colsumsq[c1], q1); }
}

// ---------------- host orchestration ----------------

static inline size_t align_up(size_t v, size_t a) { return (v + a - 1) / a * a; }

extern "C" void kernel_launch(void* const* d_in, const int* in_sizes, int n_in,
                              void* d_out, int out_size, void* d_ws, size_t ws_size,
                              hipStream_t stream) {
    const float* x_in = (const float*)d_in[0];
    const int* ei     = (const int*)d_in[1];
    const float* ew   = (const float*)d_in[2];

    char* pws = (char*)d_ws;
    size_t off_b = 0;
    auto alloc = [&](size_t bytes) -> void* {
        void* rp = pws + off_b;
        off_b = align_up(off_b + bytes, 256);
        return rp;
    };
    float* B0      = (float*)alloc((size_t)NN * 4);            // l5 h vector
    float* B1      = (float*)alloc((size_t)NN * 512 * 4);      // activations (pitched)
    unsigned short* H16 = (unsigned short*)alloc((size_t)NN * 512 * 2);  // padded pitch (64-col slabs)
    float* alpha_t = (float*)alloc((size_t)ET * 5 * 4);        // [H][ET]  (exp, unnormalized)
    unsigned short* Wt_hi = (unsigned short*)alloc((size_t)600 * 512 * 2);
    unsigned short* Wt_lo = (unsigned short*)alloc((size_t)600 * 512 * 2);
    float* al_src  = (float*)alloc((size_t)NN * 5 * 4);
    float* al_dst  = (float*)alloc((size_t)NN * 5 * 4);
    float* inv_den = (float*)alloc((size_t)NN * 5 * 4);
    float* csr_ea  = (float*)alloc((size_t)ET * 4);
    int* rankb     = (int*)alloc((size_t)ET * 4);
    int* csr_src   = (int*)alloc((size_t)ET * 4);
    int* offarr    = (int*)alloc((size_t)(NN + 1) * 4);
    float* we_dot  = (float*)alloc(40 * 4);
    // zero-region: esum + cnt + 3x colsum + 3x colsumsq (one memset)
    float* esum    = (float*)alloc(4);
    int* cnt       = (int*)alloc((size_t)NN * 4);
    float* colsum_all   = (float*)alloc(3 * 512 * 4);
    float* colsumsq_all = (float*)alloc(3 * 512 * 4);
    char* zero_end = pws + off_b;
    (void)ws_size; (void)n_in; (void)in_sizes; (void)out_size;

    int Kp[5], Np[5], hp[5];
    size_t wtoff[5];
    size_t acc_off = 0;
    for (int l = 0; l < 5; l++) {
        int K = g_cfg[l].cin, HC = g_cfg[l].C * g_cfg[l].H;
        Kp[l] = (K + 31) / 32 * 32;
        Np[l] = (HC + 127) / 128 * 128;
        hp[l] = (HC >= 64) ? ((HC + 63) / 64 * 64) : ((HC + 7) / 8 * 8);
        wtoff[l] = acc_off;
        acc_off += (size_t)Kp[l] * Np[l];
    }

    PrepArgs pa;
    for (int l = 0; l < 5; l++) {
        pa.W[l]  = (const float*)d_in[3 + l * 6 + 0];
        pa.We[l] = (const float*)d_in[3 + l * 6 + 3];
        pa.ae[l] = (const float*)d_in[3 + l * 6 + 4];
        pa.bh[l] = Wt_hi + wtoff[l];
        pa.bl[l] = Wt_lo + wtoff[l];
        pa.K[l] = g_cfg[l].cin;
        pa.N[l] = g_cfg[l].C * g_cfg[l].H;
        pa.Kp[l] = Kp[l];
        pa.Np[l] = Np[l];
        pa.C[l] = g_cfg[l].C;
        pa.H[l] = g_cfg[l].H;
    }
    pa.wedot = we_dot;

    hipMemsetAsync(esum, 0, (size_t)(zero_end - (char*)esum), stream);
    int ebl = EBLK;
    prep_fused_kernel<<<ebl + 256 + 1280, 256, 0, stream>>>(ei, rankb, cnt, ew, esum, pa);
    scan_kernel<<<1, 1024, 0, stream>>>(cnt, offarr);
    fill_kernel<<<ebl, 256, 0, stream>>>(ei, rankb, ew, esum, offarr, csr_src, csr_ea);

    for (int l = 0; l < 5; l++) {
        const LayerCfg& cf = g_cfg[l];
        int H = cf.H, C = cf.C;
        int HC = H * C;
        const float* a_s = (const float*)d_in[3 + l * 6 + 1];
        const float* a_d = (const float*)d_in[3 + l * 6 + 2];
        const float* b   = (const float*)d_in[3 + l * 6 + 5];

        const float* X = (l == 0) ? x_in : B1;
        float* outbuf = (l == 4) ? (float*)d_out : B1;
        int opitch = (l == 4) ? 1 : Kp[l + 1];
        int NH = NN * H;
        int alblocks = (NN * 64 + 255) / 256;

        if (l == 4) {
            gemv_l5_kernel<<<(NN + 255) / 256, 256, 0, stream>>>(
                X, pa.W[4], a_s, a_d, B0, al_src, al_dst);
        } else {
            const float* cs = (l >= 1) ? colsum_all + (l - 1) * 512 : nullptr;
            const float* cq = (l >= 1) ? colsumsq_all + (l - 1) * 512 : nullptr;
            const float* gg = (l >= 1) ? (const float*)d_in[33 + (l - 1) * 2 + 0] : nullptr;
            const float* bb = (l >= 1) ? (const float*)d_in[33 + (l - 1) * 2 + 1] : nullptr;
            int Din = (l >= 1) ? g_cfg[l - 1].C * g_cfg[l - 1].H : 0;
            dim3 ggrid(Np[l] / GBNT, (NN + GBM - 1) / GBM);
            gemm_split_kernel<<<ggrid, 256, 0, stream>>>(X, Wt_hi + wtoff[l], Wt_lo + wtoff[l],
                                                         nullptr, H16,
                                                         NN, Kp[l], hp[l], cs, cq, gg, bb, Din);
            al_wave_h16_kernel<<<alblocks, 256, 0, stream>>>(H16, a_s, a_d, al_src, al_dst, H, C, hp[l]);
        }

        attn_kernel<<<(NH + 255) / 256, 256, 0, stream>>>(al_src, al_dst, csr_src, csr_ea,
                                                          we_dot + l * 8, offarr, alpha_t,
                                                          inv_den, H, NH);

        if (l == 4) {
            aggregate_kernel<<<(NN + 255) / 256, 256, 0, stream>>>(
                B0, alpha_t, offarr, csr_src, b, inv_den, outbuf, NN);
        } else {
            int cps = (hp[l] >= 64) ? 16 : 8;
            int lcps = (cps == 16) ? 4 : 3;
            int slabcols = cps * 4;
            int nslabs = hp[l] / slabcols;
            int lns = (nslabs == 8) ? 3 : (nslabs == 4) ? 2 : (nslabs == 2) ? 1 : 0;
            int dup = 8 / nslabs;
            int npr = NN / dup;           // 30000 divisible by 1,2,4,8
            int G = 256 / cps;
            int gx = 8 * ((npr + G - 1) / G);
            int nhs = 1;
            for (int sbi = 0; sbi < nslabs; sbi++) {
                int j0 = sbi * slabcols;
                int span = (j0 + slabcols - 1) / C - j0 / C + 1;
                if (span > nhs) nhs = span;
            }
            int algstr = nhs * AL_ROW + 4;   // bank-staggered group stride (floats)
            int tight = ((C & 3) == 0) ? 1 : 0;  // C%4==0 -> no chunk straddles a head
            size_t smem = (size_t)G * IDX_STR * 4 + (size_t)G * algstr * 4;
            aggregate_slab_lds_kernel<<<gx, 256, smem, stream>>>(
                H16, alpha_t, offarr, csr_src, b, inv_den, outbuf,
                C, H, HC, hp[l], lns, lcps, npr, nhs, algstr, tight,
                (l == 3) ? 1 : 0, opitch);
        }

        if (l < 3) {
            bn_stats_kernel<<<512, 256, 0, stream>>>(outbuf, colsum_all + l * 512,
                                                     colsumsq_all + l * 512, HC, opitch);
        }
    }
}

// Round 10
// 735.523 us; speedup vs baseline: 1.1851x; 1.0138x over previous
//
#include <hip/hip_runtime.h>
#include <hip/hip_bf16.h>
#include <math.h>

// ---------------- problem constants ----------------
#define NN 30000
#define EE 480000
#define ET (EE + NN)   // edges + self loops = 510000
#define NEG_SLOPE 0.2f
#define BN_EPS 1e-5f

struct LayerCfg { int cin, C, H; };
static const LayerCfg g_cfg[5] = {
    {128, 100, 5}, {500, 50, 5}, {250, 32, 4}, {128, 8, 4}, {32, 1, 1}
};

typedef short short8 __attribute__((ext_vector_type(8)));
typedef float f32x4 __attribute__((ext_vector_type(4)));

__device__ __forceinline__ unsigned short f2bf(float f) {
    unsigned int u = __builtin_bit_cast(unsigned int, f);
    u = (u + 0x7FFFu + ((u >> 16) & 1u)) >> 16;
    return (unsigned short)u;
}
__device__ __forceinline__ float bf2f(unsigned short h) {
    unsigned int u = ((unsigned int)h) << 16;
    return __builtin_bit_cast(float, u);
}

// ---------------- all-layer weight prep args ----------------

struct PrepArgs {
    const float* W[5];
    const float* We[5];
    const float* ae[5];
    unsigned short* bh[5];
    unsigned short* bl[5];
    float* wedot;            // out: [5][8]
    int K[5], N[5], Kp[5], Np[5], C[5], H[5];
};

// fused independent prep: build_edges histogram + edge-weight sum + weight transpose.
static const int EBLK = (ET + 255) / 256;

__global__ void prep_fused_kernel(const int* __restrict__ ei, int* __restrict__ rank,
                                  int* __restrict__ cnt, const float* __restrict__ ew,
                                  float* __restrict__ esum, PrepArgs a) {
    __shared__ float sdata[256];
    __shared__ float tile[32][33];
    int b = blockIdx.x;
    int tid = threadIdx.x;

    if (b < EBLK) {
        int e = b * 256 + tid;
        if (e < ET) {
            int d = (e < EE) ? ei[EE + e] : (e - EE);
            rank[e] = atomicAdd(&cnt[d], 1);
        }
        return;
    }
    b -= EBLK;
    if (b < 256) {
        float s = 0.f;
        for (int i = b * 256 + tid; i < EE; i += 65536)
            s += ew[i];
        sdata[tid] = s;
        __syncthreads();
        for (int off = 128; off > 0; off >>= 1) {
            if (tid < off) sdata[tid] += sdata[tid + off];
            __syncthreads();
        }
        if (tid == 0) atomicAdd(esum, sdata[0]);
        return;
    }
    b -= 256;
    int bx = b & 15, by = (b >> 4) & 15, bz = b >> 8;
    int l = bz;
    int tx = tid & 31, ty = tid >> 5;      // 32 x 8
    if (bx == 0 && by == 0 && ty == 0 && tx < 8) {
        int hd = tx;
        if (hd < a.H[l]) {
            int C = a.C[l];
            const float* We = a.We[l] + hd * C;
            const float* ae = a.ae[l] + hd * C;
            float s = 0.f;
            for (int c = 0; c < C; c++) s += We[c] * ae[c];
            a.wedot[l * 8 + hd] = s;
        }
    }
    int Kp = a.Kp[l], Np = a.Np[l], K = a.K[l], N = a.N[l];
    int kb = bx * 32, nb = by * 32;
    if (kb >= Kp || nb >= Np) return;
    const float* B = a.W[l];
    unsigned short* Bth = a.bh[l];
    unsigned short* Btl = a.bl[l];
#pragma unroll
    for (int i = 0; i < 4; i++) {
        int k = kb + ty + i * 8, n = nb + tx;
        tile[ty + i * 8][tx] = (k < K && n < N) ? B[(size_t)k * N + n] : 0.f;
    }
    __syncthreads();
#pragma unroll
    for (int i = 0; i < 4; i++) {
        int n = nb + ty + i * 8, k = kb + tx;
        if (n < Np && k < Kp) {
            float v = tile[tx][ty + i * 8];
            unsigned short hi = f2bf(v);
            unsigned short lo = f2bf(v - bf2f(hi));
            size_t idx = (size_t)n * Kp + k;
            Bth[idx] = hi;
            Btl[idx] = lo;
        }
    }
}

// exclusive prefix over cnt -> off
__global__ void scan_kernel(const int* __restrict__ cnt, int* __restrict__ off) {
    __shared__ int lsum[1024];
    const int T = 1024;
    int t = threadIdx.x;
    int chunk = (NN + T - 1) / T;
    int base = t * chunk;
    int end = min(NN, base + chunk);
    int s = 0;
    for (int i = base; i < end; i++) s += cnt[i];
    lsum[t] = s;
    __syncthreads();
    for (int d = 1; d < T; d <<= 1) {
        int v = (t >= d) ? lsum[t - d] : 0;
        __syncthreads();
        lsum[t] += v;
        __syncthreads();
    }
    int run = (t == 0) ? 0 : lsum[t - 1];
    for (int i = base; i < end; i++) {
        off[i] = run;
        run += cnt[i];
    }
    if (t == 0) off[NN] = ET;
}

// scatter edges to CSR order via precomputed rank — NO atomics
__global__ void fill_kernel(const int* __restrict__ ei, const int* __restrict__ rank,
                            const float* __restrict__ ew, const float* __restrict__ esum,
                            const int* __restrict__ off,
                            int* __restrict__ csr_src, float* __restrict__ csr_ea) {
    int e = blockIdx.x * blockDim.x + threadIdx.x;
    if (e >= ET) return;
    int sv, d;
    if (e < EE) { sv = ei[e]; d = ei[EE + e]; }
    else        { sv = e - EE; d = e - EE; }
    int p = off[d] + rank[e];
    csr_src[p] = sv;
    csr_ea[p]  = (e < EE) ? ew[e] : esum[0] * (1.0f / (float)EE);
}

// ---------------- split-bf16 MFMA GEMM with optional fused BN+ReLU on A ----------------
#define GBM 128
#define GBNT 128
#define GBK 32
#define ASTR 36
__global__ __launch_bounds__(256) void gemm_split_kernel(const float* __restrict__ A,
                                                         const unsigned short* __restrict__ Bt_hi,
                                                         const unsigned short* __restrict__ Bt_lo,
                                                         float* __restrict__ Cm,
                                                         unsigned short* __restrict__ Ch16,
                                                         int M, int Kp, int Nc,
                                                         const float* __restrict__ colsum,
                                                         const float* __restrict__ colsumsq,
                                                         const float* __restrict__ g,
                                                         const float* __restrict__ beta,
                                                         int D) {
    __shared__ short AsH[GBM * ASTR];
    __shared__ short AsL[GBM * ASTR];
    __shared__ short BsH[GBNT * ASTR];
    __shared__ short BsL[GBNT * ASTR];
    __shared__ float sscale[512];
    __shared__ float sshift[512];
    int tid = threadIdx.x;
    bool bn = (colsum != nullptr);
    if (bn) {
        for (int c = tid; c < Kp; c += 256) {
            float sc = 0.f, sh = 0.f;
            if (c < D) {
                float mu = colsum[c] * (1.0f / (float)NN);
                float var = colsumsq[c] * (1.0f / (float)NN) - mu * mu;
                sc = g[c] * rsqrtf(var + BN_EPS);
                sh = beta[c] - mu * sc;
            }
            sscale[c] = sc;
            sshift[c] = sh;
        }
        __syncthreads();
    }
    int wave = tid >> 6, lane = tid & 63;
    int q = lane >> 4, r = lane & 15;
    int m0 = blockIdx.y * GBM, n0 = blockIdx.x * GBNT;
    int wm = (wave & 1) * 64, wn = (wave >> 1) * 64;
    f32x4 acc[4][4];
#pragma unroll
    for (int i = 0; i < 4; i++)
#pragma unroll
        for (int j = 0; j < 4; j++) acc[i][j] = (f32x4)(0.f);

    int arow2 = tid >> 1;
    int acol2 = (tid & 1) * 16;
    int brow = tid >> 2;
    int bcol = (tid & 3) * 8;

    int ksteps = Kp / GBK;
    for (int ks = 0; ks < ksteps; ks++) {
        int k0 = ks * GBK;
        {
            int m = m0 + arow2;
            float v[16];
            if (m < M) {
                const float* Ap = A + (size_t)m * Kp + k0 + acol2;
                float4 f0 = *(const float4*)(Ap);
                float4 f1 = *(const float4*)(Ap + 4);
                float4 f2 = *(const float4*)(Ap + 8);
                float4 f3 = *(const float4*)(Ap + 12);
                v[0]=f0.x; v[1]=f0.y; v[2]=f0.z; v[3]=f0.w;
                v[4]=f1.x; v[5]=f1.y; v[6]=f1.z; v[7]=f1.w;
                v[8]=f2.x; v[9]=f2.y; v[10]=f2.z; v[11]=f2.w;
                v[12]=f3.x; v[13]=f3.y; v[14]=f3.z; v[15]=f3.w;
                if (bn) {
                    int cb = k0 + acol2;
#pragma unroll
                    for (int i = 0; i < 16; i++)
                        v[i] = fmaxf(v[i] * sscale[cb + i] + sshift[cb + i], 0.f);
                }
            } else {
#pragma unroll
                for (int i = 0; i < 16; i++) v[i] = 0.f;
            }
#pragma unroll
            for (int i = 0; i < 16; i++) {
                unsigned short hi = f2bf(v[i]);
                unsigned short lo = f2bf(v[i] - bf2f(hi));
                AsH[arow2 * ASTR + acol2 + i] = (short)hi;
                AsL[arow2 * ASTR + acol2 + i] = (short)lo;
            }
        }
#pragma unroll
        for (int p = 0; p < 2; p++) {
            int row = p * 64 + brow;
            size_t gidx = (size_t)(n0 + row) * Kp + k0 + bcol;
            *((uint4*)(BsH + row * ASTR + bcol)) = *((const uint4*)(Bt_hi + gidx));
            *((uint4*)(BsL + row * ASTR + bcol)) = *((const uint4*)(Bt_lo + gidx));
        }
        __syncthreads();
        short8 ah[4], al[4], bh[4], bl[4];
#pragma unroll
        for (int i = 0; i < 4; i++) {
            ah[i] = *((const short8*)(AsH + (wm + i * 16 + r) * ASTR + q * 8));
            al[i] = *((const short8*)(AsL + (wm + i * 16 + r) * ASTR + q * 8));
        }
#pragma unroll
        for (int j = 0; j < 4; j++) {
            bh[j] = *((const short8*)(BsH + (wn + j * 16 + r) * ASTR + q * 8));
            bl[j] = *((const short8*)(BsL + (wn + j * 16 + r) * ASTR + q * 8));
        }
#pragma unroll
        for (int i = 0; i < 4; i++)
#pragma unroll
            for (int j = 0; j < 4; j++) {
                acc[i][j] = __builtin_amdgcn_mfma_f32_16x16x32_bf16(ah[i], bh[j], acc[i][j], 0, 0, 0);
                acc[i][j] = __builtin_amdgcn_mfma_f32_16x16x32_bf16(ah[i], bl[j], acc[i][j], 0, 0, 0);
                acc[i][j] = __builtin_amdgcn_mfma_f32_16x16x32_bf16(al[i], bh[j], acc[i][j], 0, 0, 0);
            }
        __syncthreads();
    }
#pragma unroll
    for (int i = 0; i < 4; i++) {
#pragma unroll
        for (int j = 0; j < 4; j++) {
#pragma unroll
            for (int reg = 0; reg < 4; reg++) {
                int mrow = m0 + wm + i * 16 + q * 4 + reg;
                int ncol = n0 + wn + j * 16 + r;
                if (mrow < M && ncol < Nc) {
                    float val = acc[i][j][reg];
                    if (Cm)   Cm[(size_t)mrow * Nc + ncol] = val;
                    if (Ch16) Ch16[(size_t)mrow * Nc + ncol] = f2bf(val);
                }
            }
        }
    }
}

// layer-5 fused GEMV
__global__ void gemv_l5_kernel(const float* __restrict__ X, const float* __restrict__ W,
                               const float* __restrict__ a_s, const float* __restrict__ a_d,
                               float* __restrict__ h, float* __restrict__ al_src,
                               float* __restrict__ al_dst) {
    __shared__ float w[32];
    if (threadIdx.x < 32) w[threadIdx.x] = W[threadIdx.x];
    __syncthreads();
    int n = blockIdx.x * blockDim.x + threadIdx.x;
    if (n >= NN) return;
    const float* row = X + (size_t)n * 32;
    float s = 0.f;
#pragma unroll
    for (int i = 0; i < 8; i++) {
        float4 f = *(const float4*)(row + i * 4);
        s += f.x * w[i * 4] + f.y * w[i * 4 + 1] + f.z * w[i * 4 + 2] + f.w * w[i * 4 + 3];
    }
    h[n] = s;
    al_src[n] = s * a_s[0];
    al_dst[n] = s * a_d[0];
}

// wave-per-node attention dots, bf16 h (layers 1-4); HCp = padded row pitch
__global__ void al_wave_h16_kernel(const unsigned short* __restrict__ h16,
                                   const float* __restrict__ a_s,
                                   const float* __restrict__ a_d,
                                   float* __restrict__ al_src, float* __restrict__ al_dst,
                                   int H, int C, int HCp) {
    int w = (blockIdx.x * blockDim.x + threadIdx.x) >> 6;
    int lane = threadIdx.x & 63;
    if (w >= NN) return;
    const unsigned short* row = h16 + (size_t)w * HCp;
    float s1[5] = {0.f, 0.f, 0.f, 0.f, 0.f};
    float s2[5] = {0.f, 0.f, 0.f, 0.f, 0.f};
#pragma unroll
    for (int hd = 0; hd < 5; hd++) {
        if (hd >= H) break;
        int base = hd * C;
        for (int c = lane * 2; c < C; c += 128) {
            unsigned int u = *(const unsigned int*)(row + base + c);
            float v0 = bf2f((unsigned short)(u & 0xffffu));
            float v1 = bf2f((unsigned short)(u >> 16));
            s1[hd] += v0 * a_s[base + c] + v1 * a_s[base + c + 1];
            s2[hd] += v0 * a_d[base + c] + v1 * a_d[base + c + 1];
        }
    }
#pragma unroll
    for (int hd = 0; hd < 5; hd++) {
        if (hd >= H) break;
#pragma unroll
        for (int off = 32; off > 0; off >>= 1) {
            s1[hd] += __shfl_xor(s1[hd], off, 64);
            s2[hd] += __shfl_xor(s2[hd], off, 64);
        }
    }
    if (lane == 0) {
#pragma unroll
        for (int hd = 0; hd < 5; hd++) {
            if (hd >= H) break;
            al_src[(size_t)w * H + hd] = s1[hd];
            al_dst[(size_t)w * H + hd] = s2[hd];
        }
    }
}

// SINGLE-PASS attn: writes UNNORMALIZED exp(logit) to alpha[p][PH] (edge-major,
// pitch PH=H) and 1/den to inv_den[n*H+hd]. Edge-major layout makes same-node
// lanes (hd=0..H-1) write CONSECUTIVE addresses — ~5x fewer scattered write
// requests than the old [hd][ET] row layout (64 scattered 4B/wave-step -> ~13
// contiguous 16-20B chunks).
__global__ void attn_kernel(const float* __restrict__ al_src,
                            const float* __restrict__ al_dst,
                            const int* __restrict__ csr_src,
                            const float* __restrict__ csr_ea,
                            const float* __restrict__ we_dot,
                            const int* __restrict__ off,
                            float* __restrict__ alpha_t,
                            float* __restrict__ inv_den, int H, int PH, int NH) {
    int t = blockIdx.x * blockDim.x + threadIdx.x;
    if (t >= NH) return;
    int n = t / H, hd = t - n * H;
    int s = off[n], e = off[n + 1];
    float ad = al_dst[(size_t)n * H + hd];
    float wd = we_dot[hd];
    float* arow = alpha_t + hd;
    float den = 0.f;
    int p = s;
    for (; p + 3 < e; p += 4) {
        int s0 = csr_src[p], s1 = csr_src[p + 1], s2 = csr_src[p + 2], s3 = csr_src[p + 3];
        float w0 = csr_ea[p], w1 = csr_ea[p + 1], w2 = csr_ea[p + 2], w3 = csr_ea[p + 3];
        float l0 = al_src[(size_t)s0 * H + hd] + ad + w0 * wd;
        float l1 = al_src[(size_t)s1 * H + hd] + ad + w1 * wd;
        float l2 = al_src[(size_t)s2 * H + hd] + ad + w2 * wd;
        float l3 = al_src[(size_t)s3 * H + hd] + ad + w3 * wd;
        l0 = (l0 >= 0.f) ? l0 : NEG_SLOPE * l0;
        l1 = (l1 >= 0.f) ? l1 : NEG_SLOPE * l1;
        l2 = (l2 >= 0.f) ? l2 : NEG_SLOPE * l2;
        l3 = (l3 >= 0.f) ? l3 : NEG_SLOPE * l3;
        float e0 = __expf(l0), e1 = __expf(l1), e2 = __expf(l2), e3 = __expf(l3);
        arow[(size_t)p * PH] = e0;
        arow[(size_t)(p + 1) * PH] = e1;
        arow[(size_t)(p + 2) * PH] = e2;
        arow[(size_t)(p + 3) * PH] = e3;
        den += e0 + e1 + e2 + e3;
    }
    for (; p < e; p++) {
        float lg = al_src[(size_t)csr_src[p] * H + hd] + ad + csr_ea[p] * wd;
        lg = (lg >= 0.f) ? lg : NEG_SLOPE * lg;
        float ex = __expf(lg);
        arow[(size_t)p * PH] = ex;
        den += ex;
    }
    inv_den[t] = 1.f / fmaxf(den, 1e-16f);
}

// ---------------- slab-partitioned gather aggregate, LDS-staged edges ----------------
// Slab pinned to an XCD via blockIdx&7 (FETCH 262->82MB verified). csr_src (as
// PRE-MULTIPLIED byte offsets) + the slab's nhs alpha head values staged in LDS
// with bank-conflict-free padded strides (conflicts 1.13e7->3.8e5 verified).
// Alpha is edge-major [p][PH]; stage reads alpha_t[(base+q)*PH + hlo + r]
// (request count identical to the old row layout; packed lines). Stage loops
// bounded by cnt; per-LAYER `tight` specialization (C%4==0).
// NOTE r8 lesson: do NOT fuse BN column stats here (2.5x regression).
#define AGG_T 64
#define IDX_STR 68
#define AL_ROW 68
__global__ void aggregate_slab_lds_kernel(const unsigned short* __restrict__ h16,
                                          const float* __restrict__ alpha_t,
                                          const int* __restrict__ off,
                                          const int* __restrict__ csr_src,
                                          const float* __restrict__ bias,
                                          const float* __restrict__ inv_den,
                                          float* __restrict__ out,
                                          int C, int H, int PH, int HC, int hp,
                                          int lns, int lcps, int npr, int nhs,
                                          int algstr, int tight, int relu, int opitch) {
    extern __shared__ char smem[];
    int cps = 1 << lcps;
    int G = 256 >> lcps;                         // nodes per block
    int* sidx = (int*)smem;                      // [G][IDX_STR]
    float* sal = (float*)(smem + (size_t)G * IDX_STR * 4);  // [G][algstr]
    __shared__ int s_maxt;

    int vs = blockIdx.x & 7;
    int nb = blockIdx.x >> 3;
    int slab = vs & ((1 << lns) - 1);
    int rep  = vs >> lns;
    int tid = threadIdx.x;
    int lc = tid & (cps - 1);
    int g = tid >> lcps;                         // node slot within block
    int nl = nb * G + g;
    bool active = (nl < npr);
    int n = rep * npr + (active ? nl : 0);

    int slab_j = slab << (lcps + 2);
    int j = slab_j + (lc << 2);
    int hlo = slab_j / C;
    int hhi = (slab_j + (cps << 2) - 1) / C;
    if (hhi > H - 1) hhi = H - 1;
    int nval = hhi - hlo + 1;                    // valid alpha heads staged

    int hdA = j / C;
    int hdB = (j + 3) / C;
    int bnd = (hdA + 1) * C - j;
    bnd = (bnd > 4) ? 4 : bnd;
    int selA = hdA - hlo; if (selA >= nhs) selA = nhs - 1;
    int selB = hdB - hlo; if (selB >= nhs) selB = nhs - 1;
    int hA = (hdA < H) ? hdA : H - 1;            // clamped heads for inv_den
    int hB = (hdB < H) ? hdB : H - 1;

    int s = active ? off[n] : 0;
    int e = active ? off[n + 1] : 0;
    int nt = (e - s + AGG_T - 1) / AGG_T;

    if (tid == 0) s_maxt = 0;
    __syncthreads();
    if (lc == 0 && active && nt > 0) atomicMax(&s_maxt, nt);
    __syncthreads();
    int maxt = s_maxt;

    int hpb = hp << 1;                           // bytes per h16 row
    const char* hb = (const char*)(h16 + j);
    int* myidx = sidx + g * IDX_STR;
    float* myal = sal + (size_t)g * algstr;
    float ac0 = 0.f, ac1 = 0.f, ac2 = 0.f, ac3 = 0.f;

    for (int t = 0; t < maxt; t++) {
        int base = s + t * AGG_T;
        int cnt = e - base;
        if (cnt < 0) cnt = 0;
        if (cnt > AGG_T) cnt = AGG_T;
        __syncthreads();   // protect prior-iteration LDS reads before overwrite
        // stage ONLY cnt slots (was AGG_T: ~73% wasted at mean deg 17)
        for (int q = lc; q < cnt; q += cps)
            myidx[q] = csr_src[base + q] * hpb;
        for (int r = 0; r < nhs; r++) {
            bool hv = (r < nval);
            const float* ar = alpha_t + hlo + r;
            float* dst = myal + r * AL_ROW;
            for (int q = lc; q < cnt; q += cps)
                dst[q] = hv ? ar[(size_t)(base + q) * PH] : 0.f;
        }
        __syncthreads();
        if (tight) {
            // C%4==0: chunk never straddles a head boundary
            const float* aA = myal + selA * AL_ROW;
            int q = 0;
            for (; q + 3 < cnt; q += 4) {
                int b0 = myidx[q], b1 = myidx[q + 1], b2 = myidx[q + 2], b3 = myidx[q + 3];
                float a0 = aA[q], a1 = aA[q + 1], a2 = aA[q + 2], a3 = aA[q + 3];
                ushort4 u0 = *(const ushort4*)(hb + b0);
                ushort4 u1 = *(const ushort4*)(hb + b1);
                ushort4 u2 = *(const ushort4*)(hb + b2);
                ushort4 u3 = *(const ushort4*)(hb + b3);
                ac0 += a0 * bf2f(u0.x); ac1 += a0 * bf2f(u0.y);
                ac2 += a0 * bf2f(u0.z); ac3 += a0 * bf2f(u0.w);
                ac0 += a1 * bf2f(u1.x); ac1 += a1 * bf2f(u1.y);
                ac2 += a1 * bf2f(u1.z); ac3 += a1 * bf2f(u1.w);
                ac0 += a2 * bf2f(u2.x); ac1 += a2 * bf2f(u2.y);
                ac2 += a2 * bf2f(u2.z); ac3 += a2 * bf2f(u2.w);
                ac0 += a3 * bf2f(u3.x); ac1 += a3 * bf2f(u3.y);
                ac2 += a3 * bf2f(u3.z); ac3 += a3 * bf2f(u3.w);
            }
            for (; q < cnt; q++) {
                int b0 = myidx[q];
                float a0 = aA[q];
                ushort4 uv = *(const ushort4*)(hb + b0);
                ac0 += a0 * bf2f(uv.x); ac1 += a0 * bf2f(uv.y);
                ac2 += a0 * bf2f(uv.z); ac3 += a0 * bf2f(uv.w);
            }
        } else {
            const float* aA = myal + selA * AL_ROW;
            const float* aB = myal + selB * AL_ROW;
            int q = 0;
            for (; q + 3 < cnt; q += 4) {
                int b0 = myidx[q], b1 = myidx[q + 1], b2 = myidx[q + 2], b3 = myidx[q + 3];
                float a0 = aA[q], a1 = aA[q + 1], a2 = aA[q + 2], a3 = aA[q + 3];
                float c0 = aB[q], c1 = aB[q + 1], c2 = aB[q + 2], c3 = aB[q + 3];
                ushort4 u0 = *(const ushort4*)(hb + b0);
                ushort4 u1 = *(const ushort4*)(hb + b1);
                ushort4 u2 = *(const ushort4*)(hb + b2);
                ushort4 u3 = *(const ushort4*)(hb + b3);
                ac0 += ((0 < bnd) ? a0 : c0) * bf2f(u0.x);
                ac1 += ((1 < bnd) ? a0 : c0) * bf2f(u0.y);
                ac2 += ((2 < bnd) ? a0 : c0) * bf2f(u0.z);
                ac3 += ((3 < bnd) ? a0 : c0) * bf2f(u0.w);
                ac0 += ((0 < bnd) ? a1 : c1) * bf2f(u1.x);
                ac1 += ((1 < bnd) ? a1 : c1) * bf2f(u1.y);
                ac2 += ((2 < bnd) ? a1 : c1) * bf2f(u1.z);
                ac3 += ((3 < bnd) ? a1 : c1) * bf2f(u1.w);
                ac0 += ((0 < bnd) ? a2 : c2) * bf2f(u2.x);
                ac1 += ((1 < bnd) ? a2 : c2) * bf2f(u2.y);
                ac2 += ((2 < bnd) ? a2 : c2) * bf2f(u2.z);
                ac3 += ((3 < bnd) ? a2 : c2) * bf2f(u2.w);
                ac0 += ((0 < bnd) ? a3 : c3) * bf2f(u3.x);
                ac1 += ((1 < bnd) ? a3 : c3) * bf2f(u3.y);
                ac2 += ((2 < bnd) ? a3 : c3) * bf2f(u3.z);
                ac3 += ((3 < bnd) ? a3 : c3) * bf2f(u3.w);
            }
            for (; q < cnt; q++) {
                int b0 = myidx[q];
                float a0 = aA[q], c0 = aB[q];
                ushort4 uv = *(const ushort4*)(hb + b0);
                ac0 += ((0 < bnd) ? a0 : c0) * bf2f(uv.x);
                ac1 += ((1 < bnd) ? a0 : c0) * bf2f(uv.y);
                ac2 += ((2 < bnd) ? a0 : c0) * bf2f(uv.z);
                ac3 += ((3 < bnd) ? a0 : c0) * bf2f(uv.w);
            }
        }
    }
    if (!active) return;
    float invA = inv_den[(size_t)n * H + hA];
    float invB = inv_den[(size_t)n * H + hB];
    // pad heads were staged as zero -> acc already 0 there; bias 0 beyond HC
    float o0 = ac0 * ((0 < bnd) ? invA : invB) + ((j + 0 < HC) ? bias[j + 0] : 0.f);
    float o1 = ac1 * ((1 < bnd) ? invA : invB) + ((j + 1 < HC) ? bias[j + 1] : 0.f);
    float o2 = ac2 * ((2 < bnd) ? invA : invB) + ((j + 2 < HC) ? bias[j + 2] : 0.f);
    float o3 = ac3 * ((3 < bnd) ? invA : invB) + ((j + 3 < HC) ? bias[j + 3] : 0.f);
    if (relu) {
        o0 = fmaxf(o0, 0.f); o1 = fmaxf(o1, 0.f);
        o2 = fmaxf(o2, 0.f); o3 = fmaxf(o3, 0.f);
    }
    *(float4*)(out + (size_t)n * opitch + j) = make_float4(o0, o1, o2, o3);
}

// scalar fallback (layer 5, HC==1, PH==1); applies inv_den
__global__ void aggregate_kernel(const float* __restrict__ hfeat,
                                 const float* __restrict__ alpha_t,
                                 const int* __restrict__ off, const int* __restrict__ csr_src,
                                 const float* __restrict__ bias,
                                 const float* __restrict__ inv_den,
                                 float* __restrict__ out, int total) {
    int t = blockIdx.x * blockDim.x + threadIdx.x;
    if (t >= total) return;
    int n = t;
    int s = off[n], e = off[n + 1];
    float acc = 0.f;
    int p = s;
    for (; p + 3 < e; p += 4) {
        acc += alpha_t[p] * hfeat[csr_src[p]]
             + alpha_t[p + 1] * hfeat[csr_src[p + 1]]
             + alpha_t[p + 2] * hfeat[csr_src[p + 2]]
             + alpha_t[p + 3] * hfeat[csr_src[p + 3]];
    }
    for (; p < e; p++) acc += alpha_t[p] * hfeat[csr_src[p]];
    out[n] = acc * inv_den[n] + bias[0];
}

// ---------------- BN stats (pitched); 512 blocks (128 was a 5x regression: latency-bound) ----------------

__global__ void bn_stats_kernel(const float* __restrict__ x, float* __restrict__ colsum,
                                float* __restrict__ colsumsq, int D, int pitch) {
    int rows_per_block = (NN + gridDim.x - 1) / gridDim.x;
    int r0 = blockIdx.x * rows_per_block;
    int r1 = min(NN, r0 + rows_per_block);
    int c0 = threadIdx.x;
    int c1 = threadIdx.x + 256;
    float s0 = 0.f, q0 = 0.f, s1 = 0.f, q1 = 0.f;
    for (int r = r0; r < r1; r++) {
        const float* row = x + (size_t)r * pitch;
        if (c0 < D) { float v = row[c0]; s0 += v; q0 += v * v; }
        if (c1 < D) { float v = row[c1]; s1 += v; q1 += v * v; }
    }
    if (c0 < D) { atomicAdd(&colsum[c0], s0); atomicAdd(&colsumsq[c0], q0); }
    if (c1 < D) { atomicAdd(&colsum[c1], s1); atomicAdd(&colsumsq[c1], q1); }
}

// ---------------- host orchestration ----------------

static inline size_t align_up(size_t v, size_t a) { return (v + a - 1) / a * a; }

extern "C" void kernel_launch(void* const* d_in, const int* in_sizes, int n_in,
                              void* d_out, int out_size, void* d_ws, size_t ws_size,
                              hipStream_t stream) {
    const float* x_in = (const float*)d_in[0];
    const int* ei     = (const int*)d_in[1];
    const float* ew   = (const float*)d_in[2];

    char* pws = (char*)d_ws;
    size_t off_b = 0;
    auto alloc = [&](size_t bytes) -> void* {
        void* rp = pws + off_b;
        off_b = align_up(off_b + bytes, 256);
        return rp;
    };
    float* B0      = (float*)alloc((size_t)NN * 4);            // l5 h vector
    float* B1      = (float*)alloc((size_t)NN * 512 * 4);      // activations (pitched)
    unsigned short* H16 = (unsigned short*)alloc((size_t)NN * 512 * 2);  // padded pitch (64-col slabs)
    float* alpha_t = (float*)alloc((size_t)ET * 5 * 4);        // [p][PH] edge-major, exp unnormalized
    unsigned short* Wt_hi = (unsigned short*)alloc((size_t)600 * 512 * 2);
    unsigned short* Wt_lo = (unsigned short*)alloc((size_t)600 * 512 * 2);
    float* al_src  = (float*)alloc((size_t)NN * 5 * 4);
    float* al_dst  = (float*)alloc((size_t)NN * 5 * 4);
    float* inv_den = (float*)alloc((size_t)NN * 5 * 4);
    float* csr_ea  = (float*)alloc((size_t)ET * 4);
    int* rankb     = (int*)alloc((size_t)ET * 4);
    int* csr_src   = (int*)alloc((size_t)ET * 4);
    int* offarr    = (int*)alloc((size_t)(NN + 1) * 4);
    float* we_dot  = (float*)alloc(40 * 4);
    // zero-region: esum + cnt + 3x colsum + 3x colsumsq (one memset)
    float* esum    = (float*)alloc(4);
    int* cnt       = (int*)alloc((size_t)NN * 4);
    float* colsum_all   = (float*)alloc(3 * 512 * 4);
    float* colsumsq_all = (float*)alloc(3 * 512 * 4);
    char* zero_end = pws + off_b;
    (void)ws_size; (void)n_in; (void)in_sizes; (void)out_size;

    int Kp[5], Np[5], hp[5];
    size_t wtoff[5];
    size_t acc_off = 0;
    for (int l = 0; l < 5; l++) {
        int K = g_cfg[l].cin, HC = g_cfg[l].C * g_cfg[l].H;
        Kp[l] = (K + 31) / 32 * 32;
        Np[l] = (HC + 127) / 128 * 128;
        hp[l] = (HC >= 64) ? ((HC + 63) / 64 * 64) : ((HC + 7) / 8 * 8);
        wtoff[l] = acc_off;
        acc_off += (size_t)Kp[l] * Np[l];
    }

    PrepArgs pa;
    for (int l = 0; l < 5; l++) {
        pa.W[l]  = (const float*)d_in[3 + l * 6 + 0];
        pa.We[l] = (const float*)d_in[3 + l * 6 + 3];
        pa.ae[l] = (const float*)d_in[3 + l * 6 + 4];
        pa.bh[l] = Wt_hi + wtoff[l];
        pa.bl[l] = Wt_lo + wtoff[l];
        pa.K[l] = g_cfg[l].cin;
        pa.N[l] = g_cfg[l].C * g_cfg[l].H;
        pa.Kp[l] = Kp[l];
        pa.Np[l] = Np[l];
        pa.C[l] = g_cfg[l].C;
        pa.H[l] = g_cfg[l].H;
    }
    pa.wedot = we_dot;

    hipMemsetAsync(esum, 0, (size_t)(zero_end - (char*)esum), stream);
    int ebl = EBLK;
    prep_fused_kernel<<<ebl + 256 + 1280, 256, 0, stream>>>(ei, rankb, cnt, ew, esum, pa);
    scan_kernel<<<1, 1024, 0, stream>>>(cnt, offarr);
    fill_kernel<<<ebl, 256, 0, stream>>>(ei, rankb, ew, esum, offarr, csr_src, csr_ea);

    for (int l = 0; l < 5; l++) {
        const LayerCfg& cf = g_cfg[l];
        int H = cf.H, C = cf.C;
        int HC = H * C;
        int PH = H;                 // alpha pitch = heads (edge-major layout)
        const float* a_s = (const float*)d_in[3 + l * 6 + 1];
        const float* a_d = (const float*)d_in[3 + l * 6 + 2];
        const float* b   = (const float*)d_in[3 + l * 6 + 5];

        const float* X = (l == 0) ? x_in : B1;
        float* outbuf = (l == 4) ? (float*)d_out : B1;
        int opitch = (l == 4) ? 1 : Kp[l + 1];
        int NH = NN * H;
        int alblocks = (NN * 64 + 255) / 256;

        if (l == 4) {
            gemv_l5_kernel<<<(NN + 255) / 256, 256, 0, stream>>>(
                X, pa.W[4], a_s, a_d, B0, al_src, al_dst);
        } else {
            const float* cs = (l >= 1) ? colsum_all + (l - 1) * 512 : nullptr;
            const float* cq = (l >= 1) ? colsumsq_all + (l - 1) * 512 : nullptr;
            const float* gg = (l >= 1) ? (const float*)d_in[33 + (l - 1) * 2 + 0] : nullptr;
            const float* bb = (l >= 1) ? (const float*)d_in[33 + (l - 1) * 2 + 1] : nullptr;
            int Din = (l >= 1) ? g_cfg[l - 1].C * g_cfg[l - 1].H : 0;
            dim3 ggrid(Np[l] / GBNT, (NN + GBM - 1) / GBM);
            gemm_split_kernel<<<ggrid, 256, 0, stream>>>(X, Wt_hi + wtoff[l], Wt_lo + wtoff[l],
                                                         nullptr, H16,
                                                         NN, Kp[l], hp[l], cs, cq, gg, bb, Din);
            al_wave_h16_kernel<<<alblocks, 256, 0, stream>>>(H16, a_s, a_d, al_src, al_dst, H, C, hp[l]);
        }

        attn_kernel<<<(NH + 255) / 256, 256, 0, stream>>>(al_src, al_dst, csr_src, csr_ea,
                                                          we_dot + l * 8, offarr, alpha_t,
                                                          inv_den, H, PH, NH);

        if (l == 4) {
            aggregate_kernel<<<(NN + 255) / 256, 256, 0, stream>>>(
                B0, alpha_t, offarr, csr_src, b, inv_den, outbuf, NN);
        } else {
            int cps = (hp[l] >= 64) ? 16 : 8;
            int lcps = (cps == 16) ? 4 : 3;
            int slabcols = cps * 4;
            int nslabs = hp[l] / slabcols;
            int lns = (nslabs == 8) ? 3 : (nslabs == 4) ? 2 : (nslabs == 2) ? 1 : 0;
            int dup = 8 / nslabs;
            int npr = NN / dup;           // 30000 divisible by 1,2,4,8
            int G = 256 / cps;
            int gx = 8 * ((npr + G - 1) / G);
            int nhs = 1;
            for (int sbi = 0; sbi < nslabs; sbi++) {
                int j0 = sbi * slabcols;
                int span = (j0 + slabcols - 1) / C - j0 / C + 1;
                if (span > nhs) nhs = span;
            }
            int algstr = nhs * AL_ROW + 4;   // bank-staggered group stride (floats)
            int tight = ((C & 3) == 0) ? 1 : 0;  // C%4==0 -> no chunk straddles a head
            size_t smem = (size_t)G * IDX_STR * 4 + (size_t)G * algstr * 4;
            aggregate_slab_lds_kernel<<<gx, 256, smem, stream>>>(
                H16, alpha_t, offarr, csr_src, b, inv_den, outbuf,
                C, H, PH, HC, hp[l], lns, lcps, npr, nhs, algstr, tight,
                (l == 3) ? 1 : 0, opitch);
        }

        if (l < 3) {
            bn_stats_kernel<<<512, 256, 0, stream>>>(outbuf, colsum_all + l * 512,
                                                     colsumsq_all + l * 512, HC, opitch);
        }
    }
}